// Round 7
// baseline (796.607 us; speedup 1.0000x reference)
//
#include <hip/hip_runtime.h>
#include <stdint.h>

// ---------------------------------------------------------------------------
// aggregated_embedding: heap binary-tree aggregation, 11 levels.
// Per level: out = root + (elu(elu(x@WinT+b_in)@W1T+b1)@W2T+b2), x=[root,left,right]
// bf16 MFMA 16x16x32, fp32 accumulate. Round 9:
//  R6 post-mortem: fused tail REGRESSED (500-590us alone) from (1) spill --
//  WRITE 47.8MB vs 0.06 ideal, VGPR at 256-cap (acc 128 + t[16] + L-loop
//  state); (2) generic-pointer staging lambda (global|LDS from one load
//  site) forced FLAT loads, killing the LDS-reuse advantage.
//  FIX: tail reworked to 512 thr / 8 waves in a 2x4 grid: per-wave
//  acc[4][4]=64 AGPR + t[8] staging => ~185 live < 256 budget, no spill.
//  Staging split into three compile-time-distinct paths (root=Ebf global,
//  lr@L128=cur_in global, lr@L<128=Pv LDS) so Pv traffic is ds_read_b128.
//  tree_level (R4-proven) untouched; schedule unchanged.
// schedule: convert | L=1024 MT8 | L=512 MT8 | L=256 MT2 | tail(128..1)
// ws layout:
//   [0)            Ebf   32064*256 bf16
//   [16,416,768)   Winbf 256*768  bf16   (row-major [n][k] = MFMA B-frag order)
//   [16,809,984)   W1bf  256*256  bf16
//   [16,941,056)   W2bf  256*256  bf16
//   [17,072,128)   curA  64*1024*256 bf16
//   [50,626,560)   curB  64*512*256 bf16
// ---------------------------------------------------------------------------

typedef __attribute__((ext_vector_type(8))) short short8;   // 8 x bf16 frag
typedef __attribute__((ext_vector_type(4))) float f32x4;    // MFMA C/D

#define XS_STRIDE 264   // 256+8 pad: row stride 528B, b128-aligned, 2-way bank alias (free)
#define TOK_N 4095

__device__ __forceinline__ unsigned short f32_to_bf16(float f) {
    union { float f; unsigned u; } v; v.f = f;
    return (unsigned short)((v.u + 0x7fffu + ((v.u >> 16) & 1u)) >> 16);  // RNE
}
__device__ __forceinline__ float bf16_to_f32(unsigned short u) {
    union { unsigned u; float f; } v; v.u = ((unsigned)u) << 16; return v.f;
}

__global__ void convert_f32_bf16(const float* __restrict__ E,
                                 const float* __restrict__ Win,
                                 const float* __restrict__ W1,
                                 const float* __restrict__ W2,
                                 unsigned short* __restrict__ Ebf,
                                 unsigned short* __restrict__ Winbf,
                                 unsigned short* __restrict__ W1bf,
                                 unsigned short* __restrict__ W2bf) {
    const int nE = 32064 * 256, nWin = 256 * 768, nW = 256 * 256;
    const int total4 = (nE + nWin + 2 * nW) >> 2;
    for (int i = blockIdx.x * blockDim.x + threadIdx.x; i < total4;
         i += gridDim.x * blockDim.x) {
        int idx = i << 2;
        const float* src; unsigned short* dst; int off;
        if (idx < nE)                  { src = E;   dst = Ebf;   off = idx; }
        else if (idx < nE + nWin)      { src = Win; dst = Winbf; off = idx - nE; }
        else if (idx < nE + nWin + nW) { src = W1;  dst = W1bf;  off = idx - nE - nWin; }
        else                           { src = W2;  dst = W2bf;  off = idx - nE - nWin - nW; }
        float4 f = *(const float4*)(src + off);
        ushort4 o;
        o.x = f32_to_bf16(f.x); o.y = f32_to_bf16(f.y);
        o.z = f32_to_bf16(f.z); o.w = f32_to_bf16(f.w);
        *(ushort4*)(dst + off) = o;
    }
}

// ---- shared GEMM machinery (inlined into both kernels) --------------------
template<int MT>
__device__ __forceinline__ void acc_bias_init(f32x4 (&acc)[MT][4],
                                              const float* __restrict__ b,
                                              int n0, int l15) {
    float bv[4];
#pragma unroll
    for (int nt = 0; nt < 4; ++nt) bv[nt] = b[n0 + nt * 16 + l15];
#pragma unroll
    for (int mt = 0; mt < MT; ++mt)
#pragma unroll
        for (int nt = 0; nt < 4; ++nt)
            acc[mt][nt] = (f32x4){bv[nt], bv[nt], bv[nt], bv[nt]};
}

// 8 ksteps of K=256 against a [n][k] weight panel; rolling 2-kstep preload
template<int MT>
__device__ __forceinline__ void mfma_gemm(const unsigned short* Xs,
                                          f32x4 (&acc)[MT][4],
                                          const unsigned short* __restrict__ base,
                                          int nstride, int kbase,
                                          int l15, int q) {
    short8 bb[2][4];
#pragma unroll
    for (int k = 0; k < 2; ++k)
#pragma unroll
        for (int nt = 0; nt < 4; ++nt)
            bb[k][nt] = *(const short8*)(base + (size_t)(nt * 16) * nstride + kbase + k * 32);
#pragma unroll
    for (int k = 0; k < 8; ++k) {
        short8 a[MT];
#pragma unroll
        for (int mt = 0; mt < MT; ++mt)
            a[mt] = *(const short8*)(&Xs[(mt * 16 + l15) * XS_STRIDE + k * 32 + q * 8]);
#pragma unroll
        for (int mt = 0; mt < MT; ++mt)
#pragma unroll
            for (int nt = 0; nt < 4; ++nt)
                acc[mt][nt] = __builtin_amdgcn_mfma_f32_16x16x32_bf16(
                    a[mt], bb[k & 1][nt], acc[mt][nt], 0, 0, 0);
        if (k + 2 < 8) {
#pragma unroll
            for (int nt = 0; nt < 4; ++nt)
                bb[k & 1][nt] = *(const short8*)(base + (size_t)(nt * 16) * nstride + kbase + (k + 2) * 32);
        }
    }
}

template<int MT>
__device__ __forceinline__ void elu_store_Xs(unsigned short* Xs,
                                             f32x4 (&acc)[MT][4],
                                             int n0, int l15, int q) {
#pragma unroll
    for (int mt = 0; mt < MT; ++mt)
#pragma unroll
        for (int nt = 0; nt < 4; ++nt)
#pragma unroll
            for (int r = 0; r < 4; ++r) {
                float h = acc[mt][nt][r];
                h = h > 0.f ? h : (__expf(h) - 1.f);
                Xs[(mt * 16 + q * 4 + r) * XS_STRIDE + n0 + nt * 16 + l15] = f32_to_bf16(h);
            }
}

// ---------------------------------------------------------------------------
// tree_level<MT>: R4-exact. block = 256 thr (4 waves), R = MT*16 rows x 256.
// MT=8: 2 waves/EU, dynamic LDS 67.6KB, unchunked 16-deep serial gathers.
// MT<8: 4 waves/EU, register gather prefetch overlapped with GEMM.
// ---------------------------------------------------------------------------
template<int MT>
__global__ __launch_bounds__(256, (MT == 8) ? 2 : 4)
void tree_level(const int* __restrict__ tokens,
                const unsigned short* __restrict__ Ebf,
                const unsigned short* __restrict__ Win,
                const unsigned short* __restrict__ W1,
                const unsigned short* __restrict__ W2,
                const float* __restrict__ b_in,
                const float* __restrict__ b1,
                const float* __restrict__ b2,
                const unsigned short* __restrict__ cur_in,
                unsigned short* __restrict__ cur_out,
                int L, int logL, int first)
{
    constexpr int R = MT * 16;
    constexpr int GITER = R / 8;
    constexpr bool PF = (MT < 8);
    extern __shared__ unsigned short Xs[];

    const int tid  = threadIdx.x;
    const int lane = tid & 63;
    const int wid  = tid >> 6;
    const int l15  = lane & 15;
    const int q    = lane >> 4;
    const int n0   = wid * 64;
    const int blk  = blockIdx.x;
    const int c    = tid & 31;
    const int sub  = tid >> 5;

    auto gsrc = [&](int p, int r) -> const unsigned short* {
        int g = blk * R + r;
        int b = g >> logL;
        int i = g - (b << logL);
        if (p == 0) {
            int tok = tokens[b * TOK_N + (L - 1) + i];
            return Ebf + (size_t)tok * 256;
        } else if (first) {
            int tok = tokens[b * TOK_N + 2047 + 2 * i + (p - 1)];
            return Ebf + (size_t)tok * 256;
        } else {
            return cur_in + ((size_t)b * (2 * L) + 2 * i + (p - 1)) * 256;
        }
    };

    // unchunked serial stage (MT==8): 16 loads in flight (R4-proven)
    auto stage = [&](int p) {
        short8 t[GITER];
#pragma unroll
        for (int it = 0; it < GITER; ++it)
            t[it] = *(const short8*)(gsrc(p, it * 8 + sub) + c * 8);
#pragma unroll
        for (int it = 0; it < GITER; ++it)
            *(short8*)(&Xs[(it * 8 + sub) * XS_STRIDE + c * 8]) = t[it];
    };

    f32x4 acc[MT][4];
    short8 g[PF ? GITER : 1];

    // ---- phase-0 gather (root) ------------------------------------------
    if constexpr (PF) {
#pragma unroll
        for (int it = 0; it < GITER; ++it)
            g[it] = *(const short8*)(gsrc(0, it * 8 + sub) + c * 8);
#pragma unroll
        for (int it = 0; it < GITER; ++it)
            *(short8*)(&Xs[(it * 8 + sub) * XS_STRIDE + c * 8]) = g[it];
    } else {
        stage(0);
    }
    __syncthreads();

    // ---- GEMM1: 3 phases of K=256 against Win (row stride 768) ----------
    acc_bias_init<MT>(acc, b_in, n0, l15);
    const unsigned short* wbase = Win + q * 8 + (size_t)(n0 + l15) * 768;
    for (int p = 0; p < 3; ++p) {
        if constexpr (PF) {
            if (p < 2) {
#pragma unroll
                for (int it = 0; it < GITER; ++it)
                    g[it] = *(const short8*)(gsrc(p + 1, it * 8 + sub) + c * 8);
            }
        }
        mfma_gemm<MT>(Xs, acc, wbase, 768, p * 256, l15, q);
        __syncthreads();
        if (p < 2) {
            if constexpr (PF) {
#pragma unroll
                for (int it = 0; it < GITER; ++it)
                    *(short8*)(&Xs[(it * 8 + sub) * XS_STRIDE + c * 8]) = g[it];
            } else {
                stage(p + 1);
            }
            __syncthreads();
        }
    }

    elu_store_Xs<MT>(Xs, acc, n0, l15, q);
    __syncthreads();

    // ---- GEMM2 (+ root re-gather prefetch if PF) ------------------------
    acc_bias_init<MT>(acc, b1, n0, l15);
    if constexpr (PF) {
#pragma unroll
        for (int it = 0; it < GITER; ++it)
            g[it] = *(const short8*)(gsrc(0, it * 8 + sub) + c * 8);
    }
    mfma_gemm<MT>(Xs, acc, W1 + q * 8 + (size_t)(n0 + l15) * 256, 256, 0, l15, q);
    __syncthreads();

    elu_store_Xs<MT>(Xs, acc, n0, l15, q);
    __syncthreads();

    // ---- GEMM3 ----------------------------------------------------------
    acc_bias_init<MT>(acc, b2, n0, l15);
    mfma_gemm<MT>(Xs, acc, W2 + q * 8 + (size_t)(n0 + l15) * 256, 256, 0, l15, q);
    __syncthreads();
    // park root rows (bf16) in Xs for transposed access by the epilogue
    if constexpr (PF) {
#pragma unroll
        for (int it = 0; it < GITER; ++it)
            *(short8*)(&Xs[(it * 8 + sub) * XS_STRIDE + c * 8]) = g[it];
    } else {
        stage(0);
    }
    __syncthreads();

    // ---- epilogue 3: out = root + H3, coalesced via LDS -----------------
#pragma unroll
    for (int mt = 0; mt < MT; ++mt)
#pragma unroll
        for (int r = 0; r < 4; ++r) {
            int row = mt * 16 + q * 4 + r;
#pragma unroll
            for (int nt = 0; nt < 4; ++nt) {
                int col = n0 + nt * 16 + l15;
                float o = acc[mt][nt][r] + bf16_to_f32(Xs[row * XS_STRIDE + col]);
                Xs[row * XS_STRIDE + col] = f32_to_bf16(o);
            }
        }
    __syncthreads();
#pragma unroll
    for (int it = 0; it < GITER; ++it) {
        int row = it * 8 + sub;
        *(short8*)(cur_out + ((size_t)(blk * R + row)) * 256 + c * 8) =
            *(const short8*)(&Xs[row * XS_STRIDE + c * 8]);
    }
}

// ---------------------------------------------------------------------------
// tree_tail: fused levels L=128..1. One block per batch element (64 blocks),
// 512 threads (8 waves, 2x4 grid: wave (wr,wc) owns rows wr*64+[0,64) x
// cols wc*64+[0,64)). Per wave acc[4][4]=64 AGPR + t[8] staging -> no spill
// (budget 256 @ launch_bounds(512,2)). Pv LDS holds the previous level's
// output; staging paths are compile-time address-space-distinct:
// root=Ebf(global), lr@L=128=cur_in(global), lr@L<128=Pv(LDS ds_read).
// Rows i>=L are clamped duplicates (i&(L-1)); outputs masked at store.
// ---------------------------------------------------------------------------
__global__ __launch_bounds__(512, 2)
void tree_tail(const int* __restrict__ tokens,
               const unsigned short* __restrict__ Ebf,
               const unsigned short* __restrict__ Win,
               const unsigned short* __restrict__ W1,
               const unsigned short* __restrict__ W2,
               const float* __restrict__ b_in,
               const float* __restrict__ b1,
               const float* __restrict__ b2,
               const unsigned short* __restrict__ cur_in,  // L=256 output
               float* __restrict__ final_out)
{
    constexpr int MT = 4;                           // rows per wave / 16
    constexpr int GITER = 8;                        // 128 rows / 16 subs
    extern __shared__ unsigned short lds[];
    unsigned short* Xs = lds;                       // [128][XS_STRIDE]
    unsigned short* Pv = lds + 128 * XS_STRIDE;     // [128][256] prev output

    const int tid  = threadIdx.x;
    const int lane = tid & 63;
    const int wid  = tid >> 6;                      // 0..7
    const int wr   = wid >> 2;                      // 0..1 row half
    const int wc   = wid & 3;                       // 0..3 col quarter
    const int l15  = lane & 15;
    const int q    = lane >> 4;
    const int n0   = wc * 64;
    const int m0   = wr * 64;
    const int b    = blockIdx.x;                    // batch element
    const int c    = tid & 31;                      // 16B chunk in 512B row
    const int sub  = tid >> 5;                      // 0..15: 16 rows/iter

    unsigned short* XsW = Xs + m0 * XS_STRIDE;      // wave's row-half base

    f32x4 acc[MT][4];

    // root gather: always global (Ebf), rows clamped to [0,L)
    auto stg_root = [&](int L) {
        short8 t[GITER];
#pragma unroll
        for (int it = 0; it < GITER; ++it) {
            int row = it * 16 + sub;
            int il  = row & (L - 1);
            int tok = tokens[b * TOK_N + (L - 1) + il];
            t[it] = *(const short8*)(Ebf + (size_t)tok * 256 + c * 8);
        }
#pragma unroll
        for (int it = 0; it < GITER; ++it)
            *(short8*)(&Xs[(it * 16 + sub) * XS_STRIDE + c * 8]) = t[it];
    };
    // left/right at L==128: global cur_in (rows 0..127, no clamp needed)
    auto stg_lr_global = [&](int p) {
        short8 t[GITER];
#pragma unroll
        for (int it = 0; it < GITER; ++it) {
            int row = it * 16 + sub;
            t[it] = *(const short8*)(cur_in + ((size_t)b * 256 + 2 * row + (p - 1)) * 256 + c * 8);
        }
#pragma unroll
        for (int it = 0; it < GITER; ++it)
            *(short8*)(&Xs[(it * 16 + sub) * XS_STRIDE + c * 8]) = t[it];
    };
    // left/right at L<128: LDS Pv (ds_read_b128), rows clamped
    auto stg_lr_lds = [&](int p, int L) {
#pragma unroll
        for (int it = 0; it < GITER; ++it) {
            int row = it * 16 + sub;
            int il  = row & (L - 1);
            short8 t = *(const short8*)(Pv + (size_t)(2 * il + (p - 1)) * 256 + c * 8);
            *(short8*)(&Xs[row * XS_STRIDE + c * 8]) = t;
        }
    };

    for (int L = 128; L >= 1; L >>= 1) {
        stg_root(L);
        __syncthreads();

        acc_bias_init<MT>(acc, b_in, n0, l15);
        const unsigned short* wbase = Win + q * 8 + (size_t)(n0 + l15) * 768;
        for (int p = 0; p < 3; ++p) {
            mfma_gemm<MT>(XsW, acc, wbase, 768, p * 256, l15, q);
            __syncthreads();
            if (p < 2) {
                if (L == 128) stg_lr_global(p + 1);
                else          stg_lr_lds(p + 1, L);
                __syncthreads();
            }
        }

        elu_store_Xs<MT>(XsW, acc, n0, l15, q);
        __syncthreads();

        acc_bias_init<MT>(acc, b1, n0, l15);
        mfma_gemm<MT>(XsW, acc, W1 + q * 8 + (size_t)(n0 + l15) * 256, 256, 0, l15, q);
        __syncthreads();

        elu_store_Xs<MT>(XsW, acc, n0, l15, q);
        __syncthreads();

        acc_bias_init<MT>(acc, b2, n0, l15);
        mfma_gemm<MT>(XsW, acc, W2 + q * 8 + (size_t)(n0 + l15) * 256, 256, 0, l15, q);
        __syncthreads();
        stg_root(L);                                 // root re-park in Xs
        __syncthreads();

        // epilogue: out = root + H3 (+b2 in acc); masked rows -> Pv / final
        if (L == 1) {
#pragma unroll
            for (int mt = 0; mt < MT; ++mt)
#pragma unroll
                for (int r = 0; r < 4; ++r) {
                    int row = m0 + mt * 16 + q * 4 + r;
                    if (row == 0) {
#pragma unroll
                        for (int nt = 0; nt < 4; ++nt) {
                            int col = n0 + nt * 16 + l15;
                            final_out[(size_t)b * 256 + col] =
                                acc[mt][nt][r] + bf16_to_f32(Xs[row * XS_STRIDE + col]);
                        }
                    }
                }
        } else {
#pragma unroll
            for (int mt = 0; mt < MT; ++mt)
#pragma unroll
                for (int r = 0; r < 4; ++r) {
                    int row = m0 + mt * 16 + q * 4 + r;
                    if (row < L) {
#pragma unroll
                        for (int nt = 0; nt < 4; ++nt) {
                            int col = n0 + nt * 16 + l15;
                            float o = acc[mt][nt][r] + bf16_to_f32(Xs[row * XS_STRIDE + col]);
                            Pv[row * 256 + col] = f32_to_bf16(o);
                        }
                    }
                }
        }
        __syncthreads();   // Pv complete before next level stages from it
    }
}

extern "C" void kernel_launch(void* const* d_in, const int* in_sizes, int n_in,
                              void* d_out, int out_size, void* d_ws, size_t ws_size,
                              hipStream_t stream) {
    const int*   tokens = (const int*)  d_in[0];
    const float* E      = (const float*)d_in[1];
    const float* W_in   = (const float*)d_in[2];
    const float* b_in   = (const float*)d_in[3];
    const float* W1     = (const float*)d_in[4];
    const float* b1     = (const float*)d_in[5];
    const float* W2     = (const float*)d_in[6];
    const float* b2     = (const float*)d_in[7];
    float* out = (float*)d_out;
    char* ws = (char*)d_ws;

    unsigned short* Ebf   = (unsigned short*)(ws);
    unsigned short* Winbf = (unsigned short*)(ws + 16416768);
    unsigned short* W1bf  = (unsigned short*)(ws + 16809984);
    unsigned short* W2bf  = (unsigned short*)(ws + 16941056);
    unsigned short* curA  = (unsigned short*)(ws + 17072128);
    unsigned short* curB  = (unsigned short*)(ws + 50626560);

    // allow >64KB dynamic LDS (once per process)
    static bool attr_done = false;
    if (!attr_done) {
        void (*k8)(const int*, const unsigned short*, const unsigned short*,
                   const unsigned short*, const unsigned short*, const float*,
                   const float*, const float*, const unsigned short*,
                   unsigned short*, int, int, int) = tree_level<8>;
        (void)hipFuncSetAttribute(reinterpret_cast<const void*>(k8),
                                  hipFuncAttributeMaxDynamicSharedMemorySize,
                                  128 * XS_STRIDE * 2);
        (void)hipFuncSetAttribute(reinterpret_cast<const void*>(&tree_tail),
                                  hipFuncAttributeMaxDynamicSharedMemorySize,
                                  128 * XS_STRIDE * 2 + 128 * 256 * 2);
        attr_done = true;
    }

    convert_f32_bf16<<<1024, 256, 0, stream>>>(E, W_in, W1, W2,
                                               Ebf, Winbf, W1bf, W2bf);

    // L=1024 (first level, reads tokens): MT=8, 512 blocks -> curA
    tree_level<8><<<dim3(512), dim3(256), 128 * XS_STRIDE * 2, stream>>>(
        tokens, Ebf, Winbf, W1bf, W2bf, b_in, b1, b2,
        nullptr, curA, 1024, 10, 1);
    // L=512: MT=8, 256 blocks, curA -> curB
    tree_level<8><<<dim3(256), dim3(256), 128 * XS_STRIDE * 2, stream>>>(
        tokens, Ebf, Winbf, W1bf, W2bf, b_in, b1, b2,
        curA, curB, 512, 9, 0);
    // L=256: MT=2, 512 blocks, curB -> curA
    tree_level<2><<<dim3(512), dim3(256), 32 * XS_STRIDE * 2, stream>>>(
        tokens, Ebf, Winbf, W1bf, W2bf, b_in, b1, b2,
        curB, curA, 256, 8, 0);
    // fused tail L=128..1: 64 blocks (one per batch), 512 thr, curA -> out
    tree_tail<<<dim3(64), dim3(512), 128 * XS_STRIDE * 2 + 128 * 256 * 2, stream>>>(
        tokens, Ebf, Winbf, W1bf, W2bf, b_in, b1, b2, curA, out);
}

// Round 8
// 527.496 us; speedup vs baseline: 1.5102x; 1.5102x over previous
//
#include <hip/hip_runtime.h>
#include <stdint.h>

// ---------------------------------------------------------------------------
// aggregated_embedding: heap binary-tree aggregation, 11 levels.
// Per level: out = root + (elu(elu(x@WinT+b_in)@W1T+b1)@W2T+b2), x=[root,left,right]
// bf16 MFMA 16x16x32, fp32 accumulate. Round 10:
//  R7 post-mortem: 128-row fused tail spilled AGAIN (WRITE 102MB vs 64KB
//  ideal; FETCH 332MB = 64blk x 8lvl x 655KB weights re-fetched because the
//  scratch stream thrashed L2). Runtime-L loop + 3 staging lambdas defeats
//  regalloc at 128-row tiles. CONCLUSION: don't fuse L>=64.
//  THIS ROUND: revert to R4-proven per-level dispatches for L>=64; fuse only
//  L=32..1 (tree_tail32): 32-row tile, MT=2, acc=32 AGPR + t[4] -> ~110 live
//  (R2-proven spill-free pressure), Pv 16KB static LDS, levels as
//  compile-time template instantiations (no runtime-L loop), every staging
//  path address-space static. 6 dispatches + 5 global round-trips -> 1.
// schedule: convert | 1024 MT8 | 512 MT8 | 256 MT2 | 128 MT1 | 64 MT1 | tail32
// ws layout:
//   [0)            Ebf   32064*256 bf16
//   [16,416,768)   Winbf 256*768  bf16   (row-major [n][k] = MFMA B-frag order)
//   [16,809,984)   W1bf  256*256  bf16
//   [16,941,056)   W2bf  256*256  bf16
//   [17,072,128)   curA  64*1024*256 bf16
//   [50,626,560)   curB  64*512*256 bf16
// ---------------------------------------------------------------------------

typedef __attribute__((ext_vector_type(8))) short short8;   // 8 x bf16 frag
typedef __attribute__((ext_vector_type(4))) float f32x4;    // MFMA C/D

#define XS_STRIDE 264   // 256+8 pad: row stride 528B, b128-aligned, 2-way bank alias (free)
#define TOK_N 4095

__device__ __forceinline__ unsigned short f32_to_bf16(float f) {
    union { float f; unsigned u; } v; v.f = f;
    return (unsigned short)((v.u + 0x7fffu + ((v.u >> 16) & 1u)) >> 16);  // RNE
}
__device__ __forceinline__ float bf16_to_f32(unsigned short u) {
    union { unsigned u; float f; } v; v.u = ((unsigned)u) << 16; return v.f;
}

__global__ void convert_f32_bf16(const float* __restrict__ E,
                                 const float* __restrict__ Win,
                                 const float* __restrict__ W1,
                                 const float* __restrict__ W2,
                                 unsigned short* __restrict__ Ebf,
                                 unsigned short* __restrict__ Winbf,
                                 unsigned short* __restrict__ W1bf,
                                 unsigned short* __restrict__ W2bf) {
    const int nE = 32064 * 256, nWin = 256 * 768, nW = 256 * 256;
    const int total4 = (nE + nWin + 2 * nW) >> 2;
    for (int i = blockIdx.x * blockDim.x + threadIdx.x; i < total4;
         i += gridDim.x * blockDim.x) {
        int idx = i << 2;
        const float* src; unsigned short* dst; int off;
        if (idx < nE)                  { src = E;   dst = Ebf;   off = idx; }
        else if (idx < nE + nWin)      { src = Win; dst = Winbf; off = idx - nE; }
        else if (idx < nE + nWin + nW) { src = W1;  dst = W1bf;  off = idx - nE - nWin; }
        else                           { src = W2;  dst = W2bf;  off = idx - nE - nWin - nW; }
        float4 f = *(const float4*)(src + off);
        ushort4 o;
        o.x = f32_to_bf16(f.x); o.y = f32_to_bf16(f.y);
        o.z = f32_to_bf16(f.z); o.w = f32_to_bf16(f.w);
        *(ushort4*)(dst + off) = o;
    }
}

// ---- shared GEMM machinery (inlined into both kernels) --------------------
template<int MT>
__device__ __forceinline__ void acc_bias_init(f32x4 (&acc)[MT][4],
                                              const float* __restrict__ b,
                                              int n0, int l15) {
    float bv[4];
#pragma unroll
    for (int nt = 0; nt < 4; ++nt) bv[nt] = b[n0 + nt * 16 + l15];
#pragma unroll
    for (int mt = 0; mt < MT; ++mt)
#pragma unroll
        for (int nt = 0; nt < 4; ++nt)
            acc[mt][nt] = (f32x4){bv[nt], bv[nt], bv[nt], bv[nt]};
}

// 8 ksteps of K=256 against a [n][k] weight panel; rolling 2-kstep preload
template<int MT>
__device__ __forceinline__ void mfma_gemm(const unsigned short* Xs,
                                          f32x4 (&acc)[MT][4],
                                          const unsigned short* __restrict__ base,
                                          int nstride, int kbase,
                                          int l15, int q) {
    short8 bb[2][4];
#pragma unroll
    for (int k = 0; k < 2; ++k)
#pragma unroll
        for (int nt = 0; nt < 4; ++nt)
            bb[k][nt] = *(const short8*)(base + (size_t)(nt * 16) * nstride + kbase + k * 32);
#pragma unroll
    for (int k = 0; k < 8; ++k) {
        short8 a[MT];
#pragma unroll
        for (int mt = 0; mt < MT; ++mt)
            a[mt] = *(const short8*)(&Xs[(mt * 16 + l15) * XS_STRIDE + k * 32 + q * 8]);
#pragma unroll
        for (int mt = 0; mt < MT; ++mt)
#pragma unroll
            for (int nt = 0; nt < 4; ++nt)
                acc[mt][nt] = __builtin_amdgcn_mfma_f32_16x16x32_bf16(
                    a[mt], bb[k & 1][nt], acc[mt][nt], 0, 0, 0);
        if (k + 2 < 8) {
#pragma unroll
            for (int nt = 0; nt < 4; ++nt)
                bb[k & 1][nt] = *(const short8*)(base + (size_t)(nt * 16) * nstride + kbase + (k + 2) * 32);
        }
    }
}

template<int MT>
__device__ __forceinline__ void elu_store_Xs(unsigned short* Xs,
                                             f32x4 (&acc)[MT][4],
                                             int n0, int l15, int q) {
#pragma unroll
    for (int mt = 0; mt < MT; ++mt)
#pragma unroll
        for (int nt = 0; nt < 4; ++nt)
#pragma unroll
            for (int r = 0; r < 4; ++r) {
                float h = acc[mt][nt][r];
                h = h > 0.f ? h : (__expf(h) - 1.f);
                Xs[(mt * 16 + q * 4 + r) * XS_STRIDE + n0 + nt * 16 + l15] = f32_to_bf16(h);
            }
}

// ---------------------------------------------------------------------------
// tree_level<MT>: R4-exact. block = 256 thr (4 waves), R = MT*16 rows x 256.
// MT=8: 2 waves/EU, dynamic LDS 67.6KB, unchunked 16-deep serial gathers.
// MT<8: 4 waves/EU, register gather prefetch overlapped with GEMM.
// ---------------------------------------------------------------------------
template<int MT>
__global__ __launch_bounds__(256, (MT == 8) ? 2 : 4)
void tree_level(const int* __restrict__ tokens,
                const unsigned short* __restrict__ Ebf,
                const unsigned short* __restrict__ Win,
                const unsigned short* __restrict__ W1,
                const unsigned short* __restrict__ W2,
                const float* __restrict__ b_in,
                const float* __restrict__ b1,
                const float* __restrict__ b2,
                const unsigned short* __restrict__ cur_in,
                unsigned short* __restrict__ cur_out,
                int L, int logL, int first)
{
    constexpr int R = MT * 16;
    constexpr int GITER = R / 8;
    constexpr bool PF = (MT < 8);
    extern __shared__ unsigned short Xs[];

    const int tid  = threadIdx.x;
    const int lane = tid & 63;
    const int wid  = tid >> 6;
    const int l15  = lane & 15;
    const int q    = lane >> 4;
    const int n0   = wid * 64;
    const int blk  = blockIdx.x;
    const int c    = tid & 31;
    const int sub  = tid >> 5;

    auto gsrc = [&](int p, int r) -> const unsigned short* {
        int g = blk * R + r;
        int b = g >> logL;
        int i = g - (b << logL);
        if (p == 0) {
            int tok = tokens[b * TOK_N + (L - 1) + i];
            return Ebf + (size_t)tok * 256;
        } else if (first) {
            int tok = tokens[b * TOK_N + 2047 + 2 * i + (p - 1)];
            return Ebf + (size_t)tok * 256;
        } else {
            return cur_in + ((size_t)b * (2 * L) + 2 * i + (p - 1)) * 256;
        }
    };

    // unchunked serial stage (MT==8): 16 loads in flight (R4-proven)
    auto stage = [&](int p) {
        short8 t[GITER];
#pragma unroll
        for (int it = 0; it < GITER; ++it)
            t[it] = *(const short8*)(gsrc(p, it * 8 + sub) + c * 8);
#pragma unroll
        for (int it = 0; it < GITER; ++it)
            *(short8*)(&Xs[(it * 8 + sub) * XS_STRIDE + c * 8]) = t[it];
    };

    f32x4 acc[MT][4];
    short8 g[PF ? GITER : 1];

    // ---- phase-0 gather (root) ------------------------------------------
    if constexpr (PF) {
#pragma unroll
        for (int it = 0; it < GITER; ++it)
            g[it] = *(const short8*)(gsrc(0, it * 8 + sub) + c * 8);
#pragma unroll
        for (int it = 0; it < GITER; ++it)
            *(short8*)(&Xs[(it * 8 + sub) * XS_STRIDE + c * 8]) = g[it];
    } else {
        stage(0);
    }
    __syncthreads();

    // ---- GEMM1: 3 phases of K=256 against Win (row stride 768) ----------
    acc_bias_init<MT>(acc, b_in, n0, l15);
    const unsigned short* wbase = Win + q * 8 + (size_t)(n0 + l15) * 768;
    for (int p = 0; p < 3; ++p) {
        if constexpr (PF) {
            if (p < 2) {
#pragma unroll
                for (int it = 0; it < GITER; ++it)
                    g[it] = *(const short8*)(gsrc(p + 1, it * 8 + sub) + c * 8);
            }
        }
        mfma_gemm<MT>(Xs, acc, wbase, 768, p * 256, l15, q);
        __syncthreads();
        if (p < 2) {
            if constexpr (PF) {
#pragma unroll
                for (int it = 0; it < GITER; ++it)
                    *(short8*)(&Xs[(it * 8 + sub) * XS_STRIDE + c * 8]) = g[it];
            } else {
                stage(p + 1);
            }
            __syncthreads();
        }
    }

    elu_store_Xs<MT>(Xs, acc, n0, l15, q);
    __syncthreads();

    // ---- GEMM2 (+ root re-gather prefetch if PF) ------------------------
    acc_bias_init<MT>(acc, b1, n0, l15);
    if constexpr (PF) {
#pragma unroll
        for (int it = 0; it < GITER; ++it)
            g[it] = *(const short8*)(gsrc(0, it * 8 + sub) + c * 8);
    }
    mfma_gemm<MT>(Xs, acc, W1 + q * 8 + (size_t)(n0 + l15) * 256, 256, 0, l15, q);
    __syncthreads();

    elu_store_Xs<MT>(Xs, acc, n0, l15, q);
    __syncthreads();

    // ---- GEMM3 ----------------------------------------------------------
    acc_bias_init<MT>(acc, b2, n0, l15);
    mfma_gemm<MT>(Xs, acc, W2 + q * 8 + (size_t)(n0 + l15) * 256, 256, 0, l15, q);
    __syncthreads();
    // park root rows (bf16) in Xs for transposed access by the epilogue
    if constexpr (PF) {
#pragma unroll
        for (int it = 0; it < GITER; ++it)
            *(short8*)(&Xs[(it * 8 + sub) * XS_STRIDE + c * 8]) = g[it];
    } else {
        stage(0);
    }
    __syncthreads();

    // ---- epilogue 3: out = root + H3, coalesced via LDS -----------------
#pragma unroll
    for (int mt = 0; mt < MT; ++mt)
#pragma unroll
        for (int r = 0; r < 4; ++r) {
            int row = mt * 16 + q * 4 + r;
#pragma unroll
            for (int nt = 0; nt < 4; ++nt) {
                int col = n0 + nt * 16 + l15;
                float o = acc[mt][nt][r] + bf16_to_f32(Xs[row * XS_STRIDE + col]);
                Xs[row * XS_STRIDE + col] = f32_to_bf16(o);
            }
        }
    __syncthreads();
#pragma unroll
    for (int it = 0; it < GITER; ++it) {
        int row = it * 8 + sub;
        *(short8*)(cur_out + ((size_t)(blk * R + row)) * 256 + c * 8) =
            *(const short8*)(&Xs[row * XS_STRIDE + c * 8]);
    }
}

// ---------------------------------------------------------------------------
// tail_level<L,FIRST,LAST>: one fused level of the small tail. 32-row tile,
// MT=2, 256 thr / 4 waves (wave wid owns cols wid*64). Compile-time L:
// clamps (row & (L-1)) fold, staging address spaces are static.
// FIRST: left/right from cur_in (global, 2L=64 rows). else: from Pv (LDS).
// LAST (L==1): fp32 final store of row 0.
// ---------------------------------------------------------------------------
template<int L, bool FIRST, bool LAST>
__device__ __forceinline__ void tail_level(
    const int* __restrict__ tokens,
    const unsigned short* __restrict__ Ebf,
    const unsigned short* __restrict__ Win,
    const unsigned short* __restrict__ W1,
    const unsigned short* __restrict__ W2,
    const float* __restrict__ b_in,
    const float* __restrict__ b1,
    const float* __restrict__ b2,
    const unsigned short* __restrict__ cur_in,
    float* __restrict__ final_out,
    unsigned short* Xs, unsigned short* Pv,
    int b, int n0, int l15, int q, int c, int sub)
{
    constexpr int MT = 2;

    auto stg_root = [&]() {
        short8 t[4];
#pragma unroll
        for (int it = 0; it < 4; ++it) {
            int row = it * 8 + sub;
            int il  = row & (L - 1);
            int tok = tokens[b * TOK_N + (L - 1) + il];
            t[it] = *(const short8*)(Ebf + (size_t)tok * 256 + c * 8);
        }
#pragma unroll
        for (int it = 0; it < 4; ++it)
            *(short8*)(&Xs[(it * 8 + sub) * XS_STRIDE + c * 8]) = t[it];
    };
    auto stg_lr = [&](int p) {
        if constexpr (FIRST) {
            short8 t[4];
#pragma unroll
            for (int it = 0; it < 4; ++it) {
                int row = it * 8 + sub;
                int il  = row & (L - 1);
                t[it] = *(const short8*)(cur_in + ((size_t)b * (2 * L) + 2 * il + (p - 1)) * 256 + c * 8);
            }
#pragma unroll
            for (int it = 0; it < 4; ++it)
                *(short8*)(&Xs[(it * 8 + sub) * XS_STRIDE + c * 8]) = t[it];
        } else {
#pragma unroll
            for (int it = 0; it < 4; ++it) {
                int row = it * 8 + sub;
                int il  = row & (L - 1);
                short8 t = *(const short8*)(Pv + (size_t)(2 * il + (p - 1)) * 256 + c * 8);
                *(short8*)(&Xs[row * XS_STRIDE + c * 8]) = t;
            }
        }
    };

    f32x4 acc[MT][4];

    stg_root();
    __syncthreads();

    acc_bias_init<MT>(acc, b_in, n0, l15);
    const unsigned short* wbase = Win + q * 8 + (size_t)(n0 + l15) * 768;
#pragma unroll
    for (int p = 0; p < 3; ++p) {
        mfma_gemm<MT>(Xs, acc, wbase, 768, p * 256, l15, q);
        __syncthreads();
        if (p < 2) { stg_lr(p + 1); __syncthreads(); }
    }

    elu_store_Xs<MT>(Xs, acc, n0, l15, q);
    __syncthreads();

    acc_bias_init<MT>(acc, b1, n0, l15);
    mfma_gemm<MT>(Xs, acc, W1 + q * 8 + (size_t)(n0 + l15) * 256, 256, 0, l15, q);
    __syncthreads();

    elu_store_Xs<MT>(Xs, acc, n0, l15, q);
    __syncthreads();

    acc_bias_init<MT>(acc, b2, n0, l15);
    mfma_gemm<MT>(Xs, acc, W2 + q * 8 + (size_t)(n0 + l15) * 256, 256, 0, l15, q);
    __syncthreads();
    stg_root();                                      // re-park root in Xs
    __syncthreads();

    if constexpr (LAST) {
#pragma unroll
        for (int mt = 0; mt < MT; ++mt)
#pragma unroll
            for (int r = 0; r < 4; ++r) {
                int row = mt * 16 + q * 4 + r;
                if (row == 0) {
#pragma unroll
                    for (int nt = 0; nt < 4; ++nt) {
                        int col = n0 + nt * 16 + l15;
                        final_out[(size_t)b * 256 + col] =
                            acc[mt][nt][r] + bf16_to_f32(Xs[row * XS_STRIDE + col]);
                    }
                }
            }
    } else {
#pragma unroll
        for (int mt = 0; mt < MT; ++mt)
#pragma unroll
            for (int r = 0; r < 4; ++r) {
                int row = mt * 16 + q * 4 + r;
                if (row < L) {
#pragma unroll
                    for (int nt = 0; nt < 4; ++nt) {
                        int col = n0 + nt * 16 + l15;
                        float o = acc[mt][nt][r] + bf16_to_f32(Xs[row * XS_STRIDE + col]);
                        Pv[row * 256 + col] = f32_to_bf16(o);
                    }
                }
            }
    }
    __syncthreads();   // Pv complete before next level stages from it
}

// fused tail L=32..1: 64 blocks (one per batch), 256 thr, static LDS 33KB
__global__ __launch_bounds__(256, 4)
void tree_tail32(const int* __restrict__ tokens,
                 const unsigned short* __restrict__ Ebf,
                 const unsigned short* __restrict__ Win,
                 const unsigned short* __restrict__ W1,
                 const unsigned short* __restrict__ W2,
                 const float* __restrict__ b_in,
                 const float* __restrict__ b1,
                 const float* __restrict__ b2,
                 const unsigned short* __restrict__ cur_in,  // L=64 output
                 float* __restrict__ final_out)
{
    __shared__ unsigned short Xs[32 * XS_STRIDE];   // 16.9 KB
    __shared__ unsigned short Pv[32 * 256];         // 16.0 KB

    const int tid  = threadIdx.x;
    const int lane = tid & 63;
    const int wid  = tid >> 6;
    const int l15  = lane & 15;
    const int q    = lane >> 4;
    const int n0   = wid * 64;
    const int b    = blockIdx.x;
    const int c    = tid & 31;
    const int sub  = tid >> 5;

    tail_level<32, true,  false>(tokens, Ebf, Win, W1, W2, b_in, b1, b2,
                                 cur_in, final_out, Xs, Pv, b, n0, l15, q, c, sub);
    tail_level<16, false, false>(tokens, Ebf, Win, W1, W2, b_in, b1, b2,
                                 cur_in, final_out, Xs, Pv, b, n0, l15, q, c, sub);
    tail_level<8,  false, false>(tokens, Ebf, Win, W1, W2, b_in, b1, b2,
                                 cur_in, final_out, Xs, Pv, b, n0, l15, q, c, sub);
    tail_level<4,  false, false>(tokens, Ebf, Win, W1, W2, b_in, b1, b2,
                                 cur_in, final_out, Xs, Pv, b, n0, l15, q, c, sub);
    tail_level<2,  false, false>(tokens, Ebf, Win, W1, W2, b_in, b1, b2,
                                 cur_in, final_out, Xs, Pv, b, n0, l15, q, c, sub);
    tail_level<1,  false, true >(tokens, Ebf, Win, W1, W2, b_in, b1, b2,
                                 cur_in, final_out, Xs, Pv, b, n0, l15, q, c, sub);
}

extern "C" void kernel_launch(void* const* d_in, const int* in_sizes, int n_in,
                              void* d_out, int out_size, void* d_ws, size_t ws_size,
                              hipStream_t stream) {
    const int*   tokens = (const int*)  d_in[0];
    const float* E      = (const float*)d_in[1];
    const float* W_in   = (const float*)d_in[2];
    const float* b_in   = (const float*)d_in[3];
    const float* W1     = (const float*)d_in[4];
    const float* b1     = (const float*)d_in[5];
    const float* W2     = (const float*)d_in[6];
    const float* b2     = (const float*)d_in[7];
    float* out = (float*)d_out;
    char* ws = (char*)d_ws;

    unsigned short* Ebf   = (unsigned short*)(ws);
    unsigned short* Winbf = (unsigned short*)(ws + 16416768);
    unsigned short* W1bf  = (unsigned short*)(ws + 16809984);
    unsigned short* W2bf  = (unsigned short*)(ws + 16941056);
    unsigned short* curA  = (unsigned short*)(ws + 17072128);
    unsigned short* curB  = (unsigned short*)(ws + 50626560);

    // allow 67.6KB dynamic LDS for the MT=8 instantiation (once per process)
    static bool attr_done = false;
    if (!attr_done) {
        void (*k8)(const int*, const unsigned short*, const unsigned short*,
                   const unsigned short*, const unsigned short*, const float*,
                   const float*, const float*, const unsigned short*,
                   unsigned short*, int, int, int) = tree_level<8>;
        (void)hipFuncSetAttribute(reinterpret_cast<const void*>(k8),
                                  hipFuncAttributeMaxDynamicSharedMemorySize,
                                  128 * XS_STRIDE * 2);
        attr_done = true;
    }

    convert_f32_bf16<<<1024, 256, 0, stream>>>(E, W_in, W1, W2,
                                               Ebf, Winbf, W1bf, W2bf);

    // L=1024 (first level, reads tokens): MT=8, 512 blocks -> curA
    tree_level<8><<<dim3(512), dim3(256), 128 * XS_STRIDE * 2, stream>>>(
        tokens, Ebf, Winbf, W1bf, W2bf, b_in, b1, b2,
        nullptr, curA, 1024, 10, 1);
    // L=512: MT=8, 256 blocks, curA -> curB
    tree_level<8><<<dim3(256), dim3(256), 128 * XS_STRIDE * 2, stream>>>(
        tokens, Ebf, Winbf, W1bf, W2bf, b_in, b1, b2,
        curA, curB, 512, 9, 0);
    // L=256: MT=2, 512 blocks, curB -> curA
    tree_level<2><<<dim3(512), dim3(256), 32 * XS_STRIDE * 2, stream>>>(
        tokens, Ebf, Winbf, W1bf, W2bf, b_in, b1, b2,
        curB, curA, 256, 8, 0);
    // L=128: MT=1, 512 blocks, curA -> curB
    tree_level<1><<<dim3(512), dim3(256), 16 * XS_STRIDE * 2, stream>>>(
        tokens, Ebf, Winbf, W1bf, W2bf, b_in, b1, b2,
        curA, curB, 128, 7, 0);
    // L=64: MT=1, 256 blocks, curB -> curA
    tree_level<1><<<dim3(256), dim3(256), 16 * XS_STRIDE * 2, stream>>>(
        tokens, Ebf, Winbf, W1bf, W2bf, b_in, b1, b2,
        curB, curA, 64, 6, 0);
    // fused tail L=32..1: 64 blocks (one per batch), curA -> out
    tree_tail32<<<dim3(64), dim3(256), 0, stream>>>(
        tokens, Ebf, Winbf, W1bf, W2bf, b_in, b1, b2, curA, out);
}

// Round 9
// 487.995 us; speedup vs baseline: 1.6324x; 1.0809x over previous
//
#include <hip/hip_runtime.h>
#include <stdint.h>

// ---------------------------------------------------------------------------
// aggregated_embedding: heap binary-tree aggregation, 11 levels.
// Per level: out = root + (elu(elu(x@WinT+b_in)@W1T+b1)@W2T+b2), x=[root,left,right]
// bf16 MFMA 16x16x32, fp32 accumulate. Round 11:
//  R8 post-mortem: fused tail clean (no big spill) but 185us @ MfmaUtil 1.5%
//  = 98% stall. Cause: 2-deep rolling B preload covers 40cy vs ~300cy L2
//  latency at 1 block/CU (no TLP). Compute floor is ~4us.
//  FIX (tail only): mfma_gemm_deep -- preload ALL 8 ksteps of B-frags
//  (32 short8 = 128 VGPR) before the MFMA chain: one L2 wait per phase
//  instead of 8. launch_bounds(256,2) gives the 256-VGPR budget (free:
//  only 64 blocks). Root gather kept in regs across the level (re-park
//  without re-gather). tree_level (R4-proven) untouched.
// schedule: convert | 1024 MT8 | 512 MT8 | 256 MT2 | 128 MT1 | 64 MT1 | tail32
// ws layout:
//   [0)            Ebf   32064*256 bf16
//   [16,416,768)   Winbf 256*768  bf16   (row-major [n][k] = MFMA B-frag order)
//   [16,809,984)   W1bf  256*256  bf16
//   [16,941,056)   W2bf  256*256  bf16
//   [17,072,128)   curA  64*1024*256 bf16
//   [50,626,560)   curB  64*512*256 bf16
// ---------------------------------------------------------------------------

typedef __attribute__((ext_vector_type(8))) short short8;   // 8 x bf16 frag
typedef __attribute__((ext_vector_type(4))) float f32x4;    // MFMA C/D

#define XS_STRIDE 264   // 256+8 pad: row stride 528B, b128-aligned, 2-way bank alias (free)
#define TOK_N 4095

__device__ __forceinline__ unsigned short f32_to_bf16(float f) {
    union { float f; unsigned u; } v; v.f = f;
    return (unsigned short)((v.u + 0x7fffu + ((v.u >> 16) & 1u)) >> 16);  // RNE
}
__device__ __forceinline__ float bf16_to_f32(unsigned short u) {
    union { unsigned u; float f; } v; v.u = ((unsigned)u) << 16; return v.f;
}

__global__ void convert_f32_bf16(const float* __restrict__ E,
                                 const float* __restrict__ Win,
                                 const float* __restrict__ W1,
                                 const float* __restrict__ W2,
                                 unsigned short* __restrict__ Ebf,
                                 unsigned short* __restrict__ Winbf,
                                 unsigned short* __restrict__ W1bf,
                                 unsigned short* __restrict__ W2bf) {
    const int nE = 32064 * 256, nWin = 256 * 768, nW = 256 * 256;
    const int total4 = (nE + nWin + 2 * nW) >> 2;
    for (int i = blockIdx.x * blockDim.x + threadIdx.x; i < total4;
         i += gridDim.x * blockDim.x) {
        int idx = i << 2;
        const float* src; unsigned short* dst; int off;
        if (idx < nE)                  { src = E;   dst = Ebf;   off = idx; }
        else if (idx < nE + nWin)      { src = Win; dst = Winbf; off = idx - nE; }
        else if (idx < nE + nWin + nW) { src = W1;  dst = W1bf;  off = idx - nE - nWin; }
        else                           { src = W2;  dst = W2bf;  off = idx - nE - nWin - nW; }
        float4 f = *(const float4*)(src + off);
        ushort4 o;
        o.x = f32_to_bf16(f.x); o.y = f32_to_bf16(f.y);
        o.z = f32_to_bf16(f.z); o.w = f32_to_bf16(f.w);
        *(ushort4*)(dst + off) = o;
    }
}

// ---- shared GEMM machinery (inlined into both kernels) --------------------
template<int MT>
__device__ __forceinline__ void acc_bias_init(f32x4 (&acc)[MT][4],
                                              const float* __restrict__ b,
                                              int n0, int l15) {
    float bv[4];
#pragma unroll
    for (int nt = 0; nt < 4; ++nt) bv[nt] = b[n0 + nt * 16 + l15];
#pragma unroll
    for (int mt = 0; mt < MT; ++mt)
#pragma unroll
        for (int nt = 0; nt < 4; ++nt)
            acc[mt][nt] = (f32x4){bv[nt], bv[nt], bv[nt], bv[nt]};
}

// 8 ksteps of K=256 against a [n][k] weight panel; rolling 2-kstep preload
// (good when TLP hides L2 latency -- the big-level kernels)
template<int MT>
__device__ __forceinline__ void mfma_gemm(const unsigned short* Xs,
                                          f32x4 (&acc)[MT][4],
                                          const unsigned short* __restrict__ base,
                                          int nstride, int kbase,
                                          int l15, int q) {
    short8 bb[2][4];
#pragma unroll
    for (int k = 0; k < 2; ++k)
#pragma unroll
        for (int nt = 0; nt < 4; ++nt)
            bb[k][nt] = *(const short8*)(base + (size_t)(nt * 16) * nstride + kbase + k * 32);
#pragma unroll
    for (int k = 0; k < 8; ++k) {
        short8 a[MT];
#pragma unroll
        for (int mt = 0; mt < MT; ++mt)
            a[mt] = *(const short8*)(&Xs[(mt * 16 + l15) * XS_STRIDE + k * 32 + q * 8]);
#pragma unroll
        for (int mt = 0; mt < MT; ++mt)
#pragma unroll
            for (int nt = 0; nt < 4; ++nt)
                acc[mt][nt] = __builtin_amdgcn_mfma_f32_16x16x32_bf16(
                    a[mt], bb[k & 1][nt], acc[mt][nt], 0, 0, 0);
        if (k + 2 < 8) {
#pragma unroll
            for (int nt = 0; nt < 4; ++nt)
                bb[k & 1][nt] = *(const short8*)(base + (size_t)(nt * 16) * nstride + kbase + (k + 2) * 32);
        }
    }
}

// full-phase B preload: all 8 ksteps (32 short8 = 128 VGPR) issued before
// the MFMA chain -- ONE L2 latency wait per phase. For latency-bound,
// low-occupancy kernels (the fused tail at 1 block/CU).
template<int MT>
__device__ __forceinline__ void mfma_gemm_deep(const unsigned short* Xs,
                                               f32x4 (&acc)[MT][4],
                                               const unsigned short* __restrict__ base,
                                               int nstride, int kbase,
                                               int l15, int q) {
    short8 bb[8][4];
#pragma unroll
    for (int k = 0; k < 8; ++k)
#pragma unroll
        for (int nt = 0; nt < 4; ++nt)
            bb[k][nt] = *(const short8*)(base + (size_t)(nt * 16) * nstride + kbase + k * 32);
#pragma unroll
    for (int k = 0; k < 8; ++k) {
        short8 a[MT];
#pragma unroll
        for (int mt = 0; mt < MT; ++mt)
            a[mt] = *(const short8*)(&Xs[(mt * 16 + l15) * XS_STRIDE + k * 32 + q * 8]);
#pragma unroll
        for (int mt = 0; mt < MT; ++mt)
#pragma unroll
            for (int nt = 0; nt < 4; ++nt)
                acc[mt][nt] = __builtin_amdgcn_mfma_f32_16x16x32_bf16(
                    a[mt], bb[k][nt], acc[mt][nt], 0, 0, 0);
    }
}

template<int MT>
__device__ __forceinline__ void elu_store_Xs(unsigned short* Xs,
                                             f32x4 (&acc)[MT][4],
                                             int n0, int l15, int q) {
#pragma unroll
    for (int mt = 0; mt < MT; ++mt)
#pragma unroll
        for (int nt = 0; nt < 4; ++nt)
#pragma unroll
            for (int r = 0; r < 4; ++r) {
                float h = acc[mt][nt][r];
                h = h > 0.f ? h : (__expf(h) - 1.f);
                Xs[(mt * 16 + q * 4 + r) * XS_STRIDE + n0 + nt * 16 + l15] = f32_to_bf16(h);
            }
}

// ---------------------------------------------------------------------------
// tree_level<MT>: R4-exact. block = 256 thr (4 waves), R = MT*16 rows x 256.
// MT=8: 2 waves/EU, dynamic LDS 67.6KB, unchunked 16-deep serial gathers.
// MT<8: 4 waves/EU, register gather prefetch overlapped with GEMM.
// ---------------------------------------------------------------------------
template<int MT>
__global__ __launch_bounds__(256, (MT == 8) ? 2 : 4)
void tree_level(const int* __restrict__ tokens,
                const unsigned short* __restrict__ Ebf,
                const unsigned short* __restrict__ Win,
                const unsigned short* __restrict__ W1,
                const unsigned short* __restrict__ W2,
                const float* __restrict__ b_in,
                const float* __restrict__ b1,
                const float* __restrict__ b2,
                const unsigned short* __restrict__ cur_in,
                unsigned short* __restrict__ cur_out,
                int L, int logL, int first)
{
    constexpr int R = MT * 16;
    constexpr int GITER = R / 8;
    constexpr bool PF = (MT < 8);
    extern __shared__ unsigned short Xs[];

    const int tid  = threadIdx.x;
    const int lane = tid & 63;
    const int wid  = tid >> 6;
    const int l15  = lane & 15;
    const int q    = lane >> 4;
    const int n0   = wid * 64;
    const int blk  = blockIdx.x;
    const int c    = tid & 31;
    const int sub  = tid >> 5;

    auto gsrc = [&](int p, int r) -> const unsigned short* {
        int g = blk * R + r;
        int b = g >> logL;
        int i = g - (b << logL);
        if (p == 0) {
            int tok = tokens[b * TOK_N + (L - 1) + i];
            return Ebf + (size_t)tok * 256;
        } else if (first) {
            int tok = tokens[b * TOK_N + 2047 + 2 * i + (p - 1)];
            return Ebf + (size_t)tok * 256;
        } else {
            return cur_in + ((size_t)b * (2 * L) + 2 * i + (p - 1)) * 256;
        }
    };

    // unchunked serial stage (MT==8): 16 loads in flight (R4-proven)
    auto stage = [&](int p) {
        short8 t[GITER];
#pragma unroll
        for (int it = 0; it < GITER; ++it)
            t[it] = *(const short8*)(gsrc(p, it * 8 + sub) + c * 8);
#pragma unroll
        for (int it = 0; it < GITER; ++it)
            *(short8*)(&Xs[(it * 8 + sub) * XS_STRIDE + c * 8]) = t[it];
    };

    f32x4 acc[MT][4];
    short8 g[PF ? GITER : 1];

    // ---- phase-0 gather (root) ------------------------------------------
    if constexpr (PF) {
#pragma unroll
        for (int it = 0; it < GITER; ++it)
            g[it] = *(const short8*)(gsrc(0, it * 8 + sub) + c * 8);
#pragma unroll
        for (int it = 0; it < GITER; ++it)
            *(short8*)(&Xs[(it * 8 + sub) * XS_STRIDE + c * 8]) = g[it];
    } else {
        stage(0);
    }
    __syncthreads();

    // ---- GEMM1: 3 phases of K=256 against Win (row stride 768) ----------
    acc_bias_init<MT>(acc, b_in, n0, l15);
    const unsigned short* wbase = Win + q * 8 + (size_t)(n0 + l15) * 768;
    for (int p = 0; p < 3; ++p) {
        if constexpr (PF) {
            if (p < 2) {
#pragma unroll
                for (int it = 0; it < GITER; ++it)
                    g[it] = *(const short8*)(gsrc(p + 1, it * 8 + sub) + c * 8);
            }
        }
        mfma_gemm<MT>(Xs, acc, wbase, 768, p * 256, l15, q);
        __syncthreads();
        if (p < 2) {
            if constexpr (PF) {
#pragma unroll
                for (int it = 0; it < GITER; ++it)
                    *(short8*)(&Xs[(it * 8 + sub) * XS_STRIDE + c * 8]) = g[it];
            } else {
                stage(p + 1);
            }
            __syncthreads();
        }
    }

    elu_store_Xs<MT>(Xs, acc, n0, l15, q);
    __syncthreads();

    // ---- GEMM2 (+ root re-gather prefetch if PF) ------------------------
    acc_bias_init<MT>(acc, b1, n0, l15);
    if constexpr (PF) {
#pragma unroll
        for (int it = 0; it < GITER; ++it)
            g[it] = *(const short8*)(gsrc(0, it * 8 + sub) + c * 8);
    }
    mfma_gemm<MT>(Xs, acc, W1 + q * 8 + (size_t)(n0 + l15) * 256, 256, 0, l15, q);
    __syncthreads();

    elu_store_Xs<MT>(Xs, acc, n0, l15, q);
    __syncthreads();

    // ---- GEMM3 ----------------------------------------------------------
    acc_bias_init<MT>(acc, b2, n0, l15);
    mfma_gemm<MT>(Xs, acc, W2 + q * 8 + (size_t)(n0 + l15) * 256, 256, 0, l15, q);
    __syncthreads();
    // park root rows (bf16) in Xs for transposed access by the epilogue
    if constexpr (PF) {
#pragma unroll
        for (int it = 0; it < GITER; ++it)
            *(short8*)(&Xs[(it * 8 + sub) * XS_STRIDE + c * 8]) = g[it];
    } else {
        stage(0);
    }
    __syncthreads();

    // ---- epilogue 3: out = root + H3, coalesced via LDS -----------------
#pragma unroll
    for (int mt = 0; mt < MT; ++mt)
#pragma unroll
        for (int r = 0; r < 4; ++r) {
            int row = mt * 16 + q * 4 + r;
#pragma unroll
            for (int nt = 0; nt < 4; ++nt) {
                int col = n0 + nt * 16 + l15;
                float o = acc[mt][nt][r] + bf16_to_f32(Xs[row * XS_STRIDE + col]);
                Xs[row * XS_STRIDE + col] = f32_to_bf16(o);
            }
        }
    __syncthreads();
#pragma unroll
    for (int it = 0; it < GITER; ++it) {
        int row = it * 8 + sub;
        *(short8*)(cur_out + ((size_t)(blk * R + row)) * 256 + c * 8) =
            *(const short8*)(&Xs[row * XS_STRIDE + c * 8]);
    }
}

// ---------------------------------------------------------------------------
// tail_level<L,FIRST,LAST>: one fused level of the small tail. 32-row tile,
// MT=2, 256 thr / 4 waves (wave wid owns cols wid*64). Compile-time L:
// clamps (row & (L-1)) fold, staging address spaces are static.
// Deep B preload (one L2 wait/phase); root kept in regs across the level.
// ---------------------------------------------------------------------------
template<int L, bool FIRST, bool LAST>
__device__ __forceinline__ void tail_level(
    const int* __restrict__ tokens,
    const unsigned short* __restrict__ Ebf,
    const unsigned short* __restrict__ Win,
    const unsigned short* __restrict__ W1,
    const unsigned short* __restrict__ W2,
    const float* __restrict__ b_in,
    const float* __restrict__ b1,
    const float* __restrict__ b2,
    const unsigned short* __restrict__ cur_in,
    float* __restrict__ final_out,
    unsigned short* Xs, unsigned short* Pv,
    int b, int n0, int l15, int q, int c, int sub)
{
    constexpr int MT = 2;

    short8 gr[4];                                    // root rows, level-persistent
    auto ld_root = [&]() {
#pragma unroll
        for (int it = 0; it < 4; ++it) {
            int row = it * 8 + sub;
            int il  = row & (L - 1);
            int tok = tokens[b * TOK_N + (L - 1) + il];
            gr[it] = *(const short8*)(Ebf + (size_t)tok * 256 + c * 8);
        }
    };
    auto park_root = [&]() {
#pragma unroll
        for (int it = 0; it < 4; ++it)
            *(short8*)(&Xs[(it * 8 + sub) * XS_STRIDE + c * 8]) = gr[it];
    };
    auto stg_lr = [&](int p) {
        if constexpr (FIRST) {
            short8 t[4];
#pragma unroll
            for (int it = 0; it < 4; ++it) {
                int row = it * 8 + sub;
                int il  = row & (L - 1);
                t[it] = *(const short8*)(cur_in + ((size_t)b * (2 * L) + 2 * il + (p - 1)) * 256 + c * 8);
            }
#pragma unroll
            for (int it = 0; it < 4; ++it)
                *(short8*)(&Xs[(it * 8 + sub) * XS_STRIDE + c * 8]) = t[it];
        } else {
#pragma unroll
            for (int it = 0; it < 4; ++it) {
                int row = it * 8 + sub;
                int il  = row & (L - 1);
                short8 t = *(const short8*)(Pv + (size_t)(2 * il + (p - 1)) * 256 + c * 8);
                *(short8*)(&Xs[row * XS_STRIDE + c * 8]) = t;
            }
        }
    };

    f32x4 acc[MT][4];

    ld_root();
    park_root();
    __syncthreads();

    acc_bias_init<MT>(acc, b_in, n0, l15);
    const unsigned short* wbase = Win + q * 8 + (size_t)(n0 + l15) * 768;
#pragma unroll
    for (int p = 0; p < 3; ++p) {
        mfma_gemm_deep<MT>(Xs, acc, wbase, 768, p * 256, l15, q);
        __syncthreads();
        if (p < 2) { stg_lr(p + 1); __syncthreads(); }
    }

    elu_store_Xs<MT>(Xs, acc, n0, l15, q);
    __syncthreads();

    acc_bias_init<MT>(acc, b1, n0, l15);
    mfma_gemm_deep<MT>(Xs, acc, W1 + q * 8 + (size_t)(n0 + l15) * 256, 256, 0, l15, q);
    __syncthreads();

    elu_store_Xs<MT>(Xs, acc, n0, l15, q);
    __syncthreads();

    acc_bias_init<MT>(acc, b2, n0, l15);
    mfma_gemm_deep<MT>(Xs, acc, W2 + q * 8 + (size_t)(n0 + l15) * 256, 256, 0, l15, q);
    __syncthreads();
    park_root();                                     // from regs, no re-gather
    __syncthreads();

    if constexpr (LAST) {
#pragma unroll
        for (int mt = 0; mt < MT; ++mt)
#pragma unroll
            for (int r = 0; r < 4; ++r) {
                int row = mt * 16 + q * 4 + r;
                if (row == 0) {
#pragma unroll
                    for (int nt = 0; nt < 4; ++nt) {
                        int col = n0 + nt * 16 + l15;
                        final_out[(size_t)b * 256 + col] =
                            acc[mt][nt][r] + bf16_to_f32(Xs[row * XS_STRIDE + col]);
                    }
                }
            }
    } else {
#pragma unroll
        for (int mt = 0; mt < MT; ++mt)
#pragma unroll
            for (int r = 0; r < 4; ++r) {
                int row = mt * 16 + q * 4 + r;
                if (row < L) {
#pragma unroll
                    for (int nt = 0; nt < 4; ++nt) {
                        int col = n0 + nt * 16 + l15;
                        float o = acc[mt][nt][r] + bf16_to_f32(Xs[row * XS_STRIDE + col]);
                        Pv[row * 256 + col] = f32_to_bf16(o);
                    }
                }
            }
    }
    __syncthreads();   // Pv complete before next level stages from it
}

// fused tail L=32..1: 64 blocks (one per batch), 256 thr, static LDS 33KB.
// launch_bounds(256,2): 256-VGPR budget for the deep preload (bb 128 + acc
// 32 + gr 16 + addr ~40 = ~215 live). Occupancy cost: none (64 blocks).
__global__ __launch_bounds__(256, 2)
void tree_tail32(const int* __restrict__ tokens,
                 const unsigned short* __restrict__ Ebf,
                 const unsigned short* __restrict__ Win,
                 const unsigned short* __restrict__ W1,
                 const unsigned short* __restrict__ W2,
                 const float* __restrict__ b_in,
                 const float* __restrict__ b1,
                 const float* __restrict__ b2,
                 const unsigned short* __restrict__ cur_in,  // L=64 output
                 float* __restrict__ final_out)
{
    __shared__ unsigned short Xs[32 * XS_STRIDE];   // 16.9 KB
    __shared__ unsigned short Pv[32 * 256];         // 16.0 KB

    const int tid  = threadIdx.x;
    const int lane = tid & 63;
    const int wid  = tid >> 6;
    const int l15  = lane & 15;
    const int q    = lane >> 4;
    const int n0   = wid * 64;
    const int b    = blockIdx.x;
    const int c    = tid & 31;
    const int sub  = tid >> 5;

    tail_level<32, true,  false>(tokens, Ebf, Win, W1, W2, b_in, b1, b2,
                                 cur_in, final_out, Xs, Pv, b, n0, l15, q, c, sub);
    tail_level<16, false, false>(tokens, Ebf, Win, W1, W2, b_in, b1, b2,
                                 cur_in, final_out, Xs, Pv, b, n0, l15, q, c, sub);
    tail_level<8,  false, false>(tokens, Ebf, Win, W1, W2, b_in, b1, b2,
                                 cur_in, final_out, Xs, Pv, b, n0, l15, q, c, sub);
    tail_level<4,  false, false>(tokens, Ebf, Win, W1, W2, b_in, b1, b2,
                                 cur_in, final_out, Xs, Pv, b, n0, l15, q, c, sub);
    tail_level<2,  false, false>(tokens, Ebf, Win, W1, W2, b_in, b1, b2,
                                 cur_in, final_out, Xs, Pv, b, n0, l15, q, c, sub);
    tail_level<1,  false, true >(tokens, Ebf, Win, W1, W2, b_in, b1, b2,
                                 cur_in, final_out, Xs, Pv, b, n0, l15, q, c, sub);
}

extern "C" void kernel_launch(void* const* d_in, const int* in_sizes, int n_in,
                              void* d_out, int out_size, void* d_ws, size_t ws_size,
                              hipStream_t stream) {
    const int*   tokens = (const int*)  d_in[0];
    const float* E      = (const float*)d_in[1];
    const float* W_in   = (const float*)d_in[2];
    const float* b_in   = (const float*)d_in[3];
    const float* W1     = (const float*)d_in[4];
    const float* b1     = (const float*)d_in[5];
    const float* W2     = (const float*)d_in[6];
    const float* b2     = (const float*)d_in[7];
    float* out = (float*)d_out;
    char* ws = (char*)d_ws;

    unsigned short* Ebf   = (unsigned short*)(ws);
    unsigned short* Winbf = (unsigned short*)(ws + 16416768);
    unsigned short* W1bf  = (unsigned short*)(ws + 16809984);
    unsigned short* W2bf  = (unsigned short*)(ws + 16941056);
    unsigned short* curA  = (unsigned short*)(ws + 17072128);
    unsigned short* curB  = (unsigned short*)(ws + 50626560);

    // allow 67.6KB dynamic LDS for the MT=8 instantiation (once per process)
    static bool attr_done = false;
    if (!attr_done) {
        void (*k8)(const int*, const unsigned short*, const unsigned short*,
                   const unsigned short*, const unsigned short*, const float*,
                   const float*, const float*, const unsigned short*,
                   unsigned short*, int, int, int) = tree_level<8>;
        (void)hipFuncSetAttribute(reinterpret_cast<const void*>(k8),
                                  hipFuncAttributeMaxDynamicSharedMemorySize,
                                  128 * XS_STRIDE * 2);
        attr_done = true;
    }

    convert_f32_bf16<<<1024, 256, 0, stream>>>(E, W_in, W1, W2,
                                               Ebf, Winbf, W1bf, W2bf);

    // L=1024 (first level, reads tokens): MT=8, 512 blocks -> curA
    tree_level<8><<<dim3(512), dim3(256), 128 * XS_STRIDE * 2, stream>>>(
        tokens, Ebf, Winbf, W1bf, W2bf, b_in, b1, b2,
        nullptr, curA, 1024, 10, 1);
    // L=512: MT=8, 256 blocks, curA -> curB
    tree_level<8><<<dim3(256), dim3(256), 128 * XS_STRIDE * 2, stream>>>(
        tokens, Ebf, Winbf, W1bf, W2bf, b_in, b1, b2,
        curA, curB, 512, 9, 0);
    // L=256: MT=2, 512 blocks, curB -> curA
    tree_level<2><<<dim3(512), dim3(256), 32 * XS_STRIDE * 2, stream>>>(
        tokens, Ebf, Winbf, W1bf, W2bf, b_in, b1, b2,
        curB, curA, 256, 8, 0);
    // L=128: MT=1, 512 blocks, curA -> curB
    tree_level<1><<<dim3(512), dim3(256), 16 * XS_STRIDE * 2, stream>>>(
        tokens, Ebf, Winbf, W1bf, W2bf, b_in, b1, b2,
        curA, curB, 128, 7, 0);
    // L=64: MT=1, 256 blocks, curB -> curA
    tree_level<1><<<dim3(256), dim3(256), 16 * XS_STRIDE * 2, stream>>>(
        tokens, Ebf, Winbf, W1bf, W2bf, b_in, b1, b2,
        curB, curA, 64, 6, 0);
    // fused tail L=32..1: 64 blocks (one per batch), curA -> out
    tree_tail32<<<dim3(64), dim3(256), 0, stream>>>(
        tokens, Ebf, Winbf, W1bf, W2bf, b_in, b1, b2, curA, out);
}

// Round 10
// 487.834 us; speedup vs baseline: 1.6329x; 1.0003x over previous
//
#include <hip/hip_runtime.h>
#include <stdint.h>

// ---------------------------------------------------------------------------
// aggregated_embedding: heap binary-tree aggregation, 11 levels.
// Per level: out = root + (elu(elu(x@WinT+b_in)@W1T+b1)@W2T+b2), x=[root,left,right]
// bf16 MFMA 16x16x32, fp32 accumulate. Round 12:
//  R9 post-mortem: deep-8 preload helped (185->144us) but bb[8][4]=128 VGPR
//  ate the whole 128-arch allocation -> compiler serialized the loads
//  (11.5k cy/phase = 32 x ~360cy SEQUENTIAL). Mechanism right, footprint
//  wrong.
//  FIX: depth-4 preload (bb[4][4]=64 VGPR, 2 rounds/phase, 16 loads
//  genuinely in flight per round; live ~110 arch, fits). Expected
//  ~1.1k cy/phase vs 11.5k. Only mfma_gemm_deep changes.
// schedule: convert | 1024 MT8 | 512 MT8 | 256 MT2 | 128 MT1 | 64 MT1 | tail32
// ws layout:
//   [0)            Ebf   32064*256 bf16
//   [16,416,768)   Winbf 256*768  bf16   (row-major [n][k] = MFMA B-frag order)
//   [16,809,984)   W1bf  256*256  bf16
//   [16,941,056)   W2bf  256*256  bf16
//   [17,072,128)   curA  64*1024*256 bf16
//   [50,626,560)   curB  64*512*256 bf16
// ---------------------------------------------------------------------------

typedef __attribute__((ext_vector_type(8))) short short8;   // 8 x bf16 frag
typedef __attribute__((ext_vector_type(4))) float f32x4;    // MFMA C/D

#define XS_STRIDE 264   // 256+8 pad: row stride 528B, b128-aligned, 2-way bank alias (free)
#define TOK_N 4095

__device__ __forceinline__ unsigned short f32_to_bf16(float f) {
    union { float f; unsigned u; } v; v.f = f;
    return (unsigned short)((v.u + 0x7fffu + ((v.u >> 16) & 1u)) >> 16);  // RNE
}
__device__ __forceinline__ float bf16_to_f32(unsigned short u) {
    union { unsigned u; float f; } v; v.u = ((unsigned)u) << 16; return v.f;
}

__global__ void convert_f32_bf16(const float* __restrict__ E,
                                 const float* __restrict__ Win,
                                 const float* __restrict__ W1,
                                 const float* __restrict__ W2,
                                 unsigned short* __restrict__ Ebf,
                                 unsigned short* __restrict__ Winbf,
                                 unsigned short* __restrict__ W1bf,
                                 unsigned short* __restrict__ W2bf) {
    const int nE = 32064 * 256, nWin = 256 * 768, nW = 256 * 256;
    const int total4 = (nE + nWin + 2 * nW) >> 2;
    for (int i = blockIdx.x * blockDim.x + threadIdx.x; i < total4;
         i += gridDim.x * blockDim.x) {
        int idx = i << 2;
        const float* src; unsigned short* dst; int off;
        if (idx < nE)                  { src = E;   dst = Ebf;   off = idx; }
        else if (idx < nE + nWin)      { src = Win; dst = Winbf; off = idx - nE; }
        else if (idx < nE + nWin + nW) { src = W1;  dst = W1bf;  off = idx - nE - nWin; }
        else                           { src = W2;  dst = W2bf;  off = idx - nE - nWin - nW; }
        float4 f = *(const float4*)(src + off);
        ushort4 o;
        o.x = f32_to_bf16(f.x); o.y = f32_to_bf16(f.y);
        o.z = f32_to_bf16(f.z); o.w = f32_to_bf16(f.w);
        *(ushort4*)(dst + off) = o;
    }
}

// ---- shared GEMM machinery (inlined into both kernels) --------------------
template<int MT>
__device__ __forceinline__ void acc_bias_init(f32x4 (&acc)[MT][4],
                                              const float* __restrict__ b,
                                              int n0, int l15) {
    float bv[4];
#pragma unroll
    for (int nt = 0; nt < 4; ++nt) bv[nt] = b[n0 + nt * 16 + l15];
#pragma unroll
    for (int mt = 0; mt < MT; ++mt)
#pragma unroll
        for (int nt = 0; nt < 4; ++nt)
            acc[mt][nt] = (f32x4){bv[nt], bv[nt], bv[nt], bv[nt]};
}

// 8 ksteps of K=256 against a [n][k] weight panel; rolling 2-kstep preload
// (good when TLP hides L2 latency -- the big-level kernels)
template<int MT>
__device__ __forceinline__ void mfma_gemm(const unsigned short* Xs,
                                          f32x4 (&acc)[MT][4],
                                          const unsigned short* __restrict__ base,
                                          int nstride, int kbase,
                                          int l15, int q) {
    short8 bb[2][4];
#pragma unroll
    for (int k = 0; k < 2; ++k)
#pragma unroll
        for (int nt = 0; nt < 4; ++nt)
            bb[k][nt] = *(const short8*)(base + (size_t)(nt * 16) * nstride + kbase + k * 32);
#pragma unroll
    for (int k = 0; k < 8; ++k) {
        short8 a[MT];
#pragma unroll
        for (int mt = 0; mt < MT; ++mt)
            a[mt] = *(const short8*)(&Xs[(mt * 16 + l15) * XS_STRIDE + k * 32 + q * 8]);
#pragma unroll
        for (int mt = 0; mt < MT; ++mt)
#pragma unroll
            for (int nt = 0; nt < 4; ++nt)
                acc[mt][nt] = __builtin_amdgcn_mfma_f32_16x16x32_bf16(
                    a[mt], bb[k & 1][nt], acc[mt][nt], 0, 0, 0);
        if (k + 2 < 8) {
#pragma unroll
            for (int nt = 0; nt < 4; ++nt)
                bb[k & 1][nt] = *(const short8*)(base + (size_t)(nt * 16) * nstride + kbase + (k + 2) * 32);
        }
    }
}

// depth-4 B preload: 2 rounds of 4 ksteps (bb[4][4] = 64 VGPR, 16 loads
// truly in flight per round) -- two L2 waits per phase. R9's depth-8
// (128 VGPR) exceeded the arch-register allocation and the compiler
// serialized all 32 loads; depth-4 is the largest footprint that fits
// alongside a[], gr[], and addressing (~110 arch live).
template<int MT>
__device__ __forceinline__ void mfma_gemm_deep(const unsigned short* Xs,
                                               f32x4 (&acc)[MT][4],
                                               const unsigned short* __restrict__ base,
                                               int nstride, int kbase,
                                               int l15, int q) {
#pragma unroll
    for (int h = 0; h < 2; ++h) {
        short8 bb[4][4];
#pragma unroll
        for (int k = 0; k < 4; ++k)
#pragma unroll
            for (int nt = 0; nt < 4; ++nt)
                bb[k][nt] = *(const short8*)(base + (size_t)(nt * 16) * nstride
                                             + kbase + (h * 4 + k) * 32);
#pragma unroll
        for (int k = 0; k < 4; ++k) {
            short8 a[MT];
#pragma unroll
            for (int mt = 0; mt < MT; ++mt)
                a[mt] = *(const short8*)(&Xs[(mt * 16 + l15) * XS_STRIDE
                                             + (h * 4 + k) * 32 + q * 8]);
#pragma unroll
            for (int mt = 0; mt < MT; ++mt)
#pragma unroll
                for (int nt = 0; nt < 4; ++nt)
                    acc[mt][nt] = __builtin_amdgcn_mfma_f32_16x16x32_bf16(
                        a[mt], bb[k][nt], acc[mt][nt], 0, 0, 0);
        }
    }
}

template<int MT>
__device__ __forceinline__ void elu_store_Xs(unsigned short* Xs,
                                             f32x4 (&acc)[MT][4],
                                             int n0, int l15, int q) {
#pragma unroll
    for (int mt = 0; mt < MT; ++mt)
#pragma unroll
        for (int nt = 0; nt < 4; ++nt)
#pragma unroll
            for (int r = 0; r < 4; ++r) {
                float h = acc[mt][nt][r];
                h = h > 0.f ? h : (__expf(h) - 1.f);
                Xs[(mt * 16 + q * 4 + r) * XS_STRIDE + n0 + nt * 16 + l15] = f32_to_bf16(h);
            }
}

// ---------------------------------------------------------------------------
// tree_level<MT>: R4-exact. block = 256 thr (4 waves), R = MT*16 rows x 256.
// MT=8: 2 waves/EU, dynamic LDS 67.6KB, unchunked 16-deep serial gathers.
// MT<8: 4 waves/EU, register gather prefetch overlapped with GEMM.
// ---------------------------------------------------------------------------
template<int MT>
__global__ __launch_bounds__(256, (MT == 8) ? 2 : 4)
void tree_level(const int* __restrict__ tokens,
                const unsigned short* __restrict__ Ebf,
                const unsigned short* __restrict__ Win,
                const unsigned short* __restrict__ W1,
                const unsigned short* __restrict__ W2,
                const float* __restrict__ b_in,
                const float* __restrict__ b1,
                const float* __restrict__ b2,
                const unsigned short* __restrict__ cur_in,
                unsigned short* __restrict__ cur_out,
                int L, int logL, int first)
{
    constexpr int R = MT * 16;
    constexpr int GITER = R / 8;
    constexpr bool PF = (MT < 8);
    extern __shared__ unsigned short Xs[];

    const int tid  = threadIdx.x;
    const int lane = tid & 63;
    const int wid  = tid >> 6;
    const int l15  = lane & 15;
    const int q    = lane >> 4;
    const int n0   = wid * 64;
    const int blk  = blockIdx.x;
    const int c    = tid & 31;
    const int sub  = tid >> 5;

    auto gsrc = [&](int p, int r) -> const unsigned short* {
        int g = blk * R + r;
        int b = g >> logL;
        int i = g - (b << logL);
        if (p == 0) {
            int tok = tokens[b * TOK_N + (L - 1) + i];
            return Ebf + (size_t)tok * 256;
        } else if (first) {
            int tok = tokens[b * TOK_N + 2047 + 2 * i + (p - 1)];
            return Ebf + (size_t)tok * 256;
        } else {
            return cur_in + ((size_t)b * (2 * L) + 2 * i + (p - 1)) * 256;
        }
    };

    // unchunked serial stage (MT==8): 16 loads in flight (R4-proven)
    auto stage = [&](int p) {
        short8 t[GITER];
#pragma unroll
        for (int it = 0; it < GITER; ++it)
            t[it] = *(const short8*)(gsrc(p, it * 8 + sub) + c * 8);
#pragma unroll
        for (int it = 0; it < GITER; ++it)
            *(short8*)(&Xs[(it * 8 + sub) * XS_STRIDE + c * 8]) = t[it];
    };

    f32x4 acc[MT][4];
    short8 g[PF ? GITER : 1];

    // ---- phase-0 gather (root) ------------------------------------------
    if constexpr (PF) {
#pragma unroll
        for (int it = 0; it < GITER; ++it)
            g[it] = *(const short8*)(gsrc(0, it * 8 + sub) + c * 8);
#pragma unroll
        for (int it = 0; it < GITER; ++it)
            *(short8*)(&Xs[(it * 8 + sub) * XS_STRIDE + c * 8]) = g[it];
    } else {
        stage(0);
    }
    __syncthreads();

    // ---- GEMM1: 3 phases of K=256 against Win (row stride 768) ----------
    acc_bias_init<MT>(acc, b_in, n0, l15);
    const unsigned short* wbase = Win + q * 8 + (size_t)(n0 + l15) * 768;
    for (int p = 0; p < 3; ++p) {
        if constexpr (PF) {
            if (p < 2) {
#pragma unroll
                for (int it = 0; it < GITER; ++it)
                    g[it] = *(const short8*)(gsrc(p + 1, it * 8 + sub) + c * 8);
            }
        }
        mfma_gemm<MT>(Xs, acc, wbase, 768, p * 256, l15, q);
        __syncthreads();
        if (p < 2) {
            if constexpr (PF) {
#pragma unroll
                for (int it = 0; it < GITER; ++it)
                    *(short8*)(&Xs[(it * 8 + sub) * XS_STRIDE + c * 8]) = g[it];
            } else {
                stage(p + 1);
            }
            __syncthreads();
        }
    }

    elu_store_Xs<MT>(Xs, acc, n0, l15, q);
    __syncthreads();

    // ---- GEMM2 (+ root re-gather prefetch if PF) ------------------------
    acc_bias_init<MT>(acc, b1, n0, l15);
    if constexpr (PF) {
#pragma unroll
        for (int it = 0; it < GITER; ++it)
            g[it] = *(const short8*)(gsrc(0, it * 8 + sub) + c * 8);
    }
    mfma_gemm<MT>(Xs, acc, W1 + q * 8 + (size_t)(n0 + l15) * 256, 256, 0, l15, q);
    __syncthreads();

    elu_store_Xs<MT>(Xs, acc, n0, l15, q);
    __syncthreads();

    // ---- GEMM3 ----------------------------------------------------------
    acc_bias_init<MT>(acc, b2, n0, l15);
    mfma_gemm<MT>(Xs, acc, W2 + q * 8 + (size_t)(n0 + l15) * 256, 256, 0, l15, q);
    __syncthreads();
    // park root rows (bf16) in Xs for transposed access by the epilogue
    if constexpr (PF) {
#pragma unroll
        for (int it = 0; it < GITER; ++it)
            *(short8*)(&Xs[(it * 8 + sub) * XS_STRIDE + c * 8]) = g[it];
    } else {
        stage(0);
    }
    __syncthreads();

    // ---- epilogue 3: out = root + H3, coalesced via LDS -----------------
#pragma unroll
    for (int mt = 0; mt < MT; ++mt)
#pragma unroll
        for (int r = 0; r < 4; ++r) {
            int row = mt * 16 + q * 4 + r;
#pragma unroll
            for (int nt = 0; nt < 4; ++nt) {
                int col = n0 + nt * 16 + l15;
                float o = acc[mt][nt][r] + bf16_to_f32(Xs[row * XS_STRIDE + col]);
                Xs[row * XS_STRIDE + col] = f32_to_bf16(o);
            }
        }
    __syncthreads();
#pragma unroll
    for (int it = 0; it < GITER; ++it) {
        int row = it * 8 + sub;
        *(short8*)(cur_out + ((size_t)(blk * R + row)) * 256 + c * 8) =
            *(const short8*)(&Xs[row * XS_STRIDE + c * 8]);
    }
}

// ---------------------------------------------------------------------------
// tail_level<L,FIRST,LAST>: one fused level of the small tail. 32-row tile,
// MT=2, 256 thr / 4 waves (wave wid owns cols wid*64). Compile-time L:
// clamps (row & (L-1)) fold, staging address spaces are static.
// Depth-4 B preload (two L2 waits/phase); root kept in regs across level.
// ---------------------------------------------------------------------------
template<int L, bool FIRST, bool LAST>
__device__ __forceinline__ void tail_level(
    const int* __restrict__ tokens,
    const unsigned short* __restrict__ Ebf,
    const unsigned short* __restrict__ Win,
    const unsigned short* __restrict__ W1,
    const unsigned short* __restrict__ W2,
    const float* __restrict__ b_in,
    const float* __restrict__ b1,
    const float* __restrict__ b2,
    const unsigned short* __restrict__ cur_in,
    float* __restrict__ final_out,
    unsigned short* Xs, unsigned short* Pv,
    int b, int n0, int l15, int q, int c, int sub)
{
    constexpr int MT = 2;

    short8 gr[4];                                    // root rows, level-persistent
    auto ld_root = [&]() {
#pragma unroll
        for (int it = 0; it < 4; ++it) {
            int row = it * 8 + sub;
            int il  = row & (L - 1);
            int tok = tokens[b * TOK_N + (L - 1) + il];
            gr[it] = *(const short8*)(Ebf + (size_t)tok * 256 + c * 8);
        }
    };
    auto park_root = [&]() {
#pragma unroll
        for (int it = 0; it < 4; ++it)
            *(short8*)(&Xs[(it * 8 + sub) * XS_STRIDE + c * 8]) = gr[it];
    };
    auto stg_lr = [&](int p) {
        if constexpr (FIRST) {
            short8 t[4];
#pragma unroll
            for (int it = 0; it < 4; ++it) {
                int row = it * 8 + sub;
                int il  = row & (L - 1);
                t[it] = *(const short8*)(cur_in + ((size_t)b * (2 * L) + 2 * il + (p - 1)) * 256 + c * 8);
            }
#pragma unroll
            for (int it = 0; it < 4; ++it)
                *(short8*)(&Xs[(it * 8 + sub) * XS_STRIDE + c * 8]) = t[it];
        } else {
#pragma unroll
            for (int it = 0; it < 4; ++it) {
                int row = it * 8 + sub;
                int il  = row & (L - 1);
                short8 t = *(const short8*)(Pv + (size_t)(2 * il + (p - 1)) * 256 + c * 8);
                *(short8*)(&Xs[row * XS_STRIDE + c * 8]) = t;
            }
        }
    };

    f32x4 acc[MT][4];

    ld_root();
    park_root();
    __syncthreads();

    acc_bias_init<MT>(acc, b_in, n0, l15);
    const unsigned short* wbase = Win + q * 8 + (size_t)(n0 + l15) * 768;
#pragma unroll
    for (int p = 0; p < 3; ++p) {
        mfma_gemm_deep<MT>(Xs, acc, wbase, 768, p * 256, l15, q);
        __syncthreads();
        if (p < 2) { stg_lr(p + 1); __syncthreads(); }
    }

    elu_store_Xs<MT>(Xs, acc, n0, l15, q);
    __syncthreads();

    acc_bias_init<MT>(acc, b1, n0, l15);
    mfma_gemm_deep<MT>(Xs, acc, W1 + q * 8 + (size_t)(n0 + l15) * 256, 256, 0, l15, q);
    __syncthreads();

    elu_store_Xs<MT>(Xs, acc, n0, l15, q);
    __syncthreads();

    acc_bias_init<MT>(acc, b2, n0, l15);
    mfma_gemm_deep<MT>(Xs, acc, W2 + q * 8 + (size_t)(n0 + l15) * 256, 256, 0, l15, q);
    __syncthreads();
    park_root();                                     // from regs, no re-gather
    __syncthreads();

    if constexpr (LAST) {
#pragma unroll
        for (int mt = 0; mt < MT; ++mt)
#pragma unroll
            for (int r = 0; r < 4; ++r) {
                int row = mt * 16 + q * 4 + r;
                if (row == 0) {
#pragma unroll
                    for (int nt = 0; nt < 4; ++nt) {
                        int col = n0 + nt * 16 + l15;
                        final_out[(size_t)b * 256 + col] =
                            acc[mt][nt][r] + bf16_to_f32(Xs[row * XS_STRIDE + col]);
                    }
                }
            }
    } else {
#pragma unroll
        for (int mt = 0; mt < MT; ++mt)
#pragma unroll
            for (int r = 0; r < 4; ++r) {
                int row = mt * 16 + q * 4 + r;
                if (row < L) {
#pragma unroll
                    for (int nt = 0; nt < 4; ++nt) {
                        int col = n0 + nt * 16 + l15;
                        float o = acc[mt][nt][r] + bf16_to_f32(Xs[row * XS_STRIDE + col]);
                        Pv[row * 256 + col] = f32_to_bf16(o);
                    }
                }
            }
    }
    __syncthreads();   // Pv complete before next level stages from it
}

// fused tail L=32..1: 64 blocks (one per batch), 256 thr, static LDS 33KB.
// launch_bounds(256,2): roomy VGPR budget (live ~110 arch + 32 AGPR).
__global__ __launch_bounds__(256, 2)
void tree_tail32(const int* __restrict__ tokens,
                 const unsigned short* __restrict__ Ebf,
                 const unsigned short* __restrict__ Win,
                 const unsigned short* __restrict__ W1,
                 const unsigned short* __restrict__ W2,
                 const float* __restrict__ b_in,
                 const float* __restrict__ b1,
                 const float* __restrict__ b2,
                 const unsigned short* __restrict__ cur_in,  // L=64 output
                 float* __restrict__ final_out)
{
    __shared__ unsigned short Xs[32 * XS_STRIDE];   // 16.9 KB
    __shared__ unsigned short Pv[32 * 256];         // 16.0 KB

    const int tid  = threadIdx.x;
    const int lane = tid & 63;
    const int wid  = tid >> 6;
    const int l15  = lane & 15;
    const int q    = lane >> 4;
    const int n0   = wid * 64;
    const int b    = blockIdx.x;
    const int c    = tid & 31;
    const int sub  = tid >> 5;

    tail_level<32, true,  false>(tokens, Ebf, Win, W1, W2, b_in, b1, b2,
                                 cur_in, final_out, Xs, Pv, b, n0, l15, q, c, sub);
    tail_level<16, false, false>(tokens, Ebf, Win, W1, W2, b_in, b1, b2,
                                 cur_in, final_out, Xs, Pv, b, n0, l15, q, c, sub);
    tail_level<8,  false, false>(tokens, Ebf, Win, W1, W2, b_in, b1, b2,
                                 cur_in, final_out, Xs, Pv, b, n0, l15, q, c, sub);
    tail_level<4,  false, false>(tokens, Ebf, Win, W1, W2, b_in, b1, b2,
                                 cur_in, final_out, Xs, Pv, b, n0, l15, q, c, sub);
    tail_level<2,  false, false>(tokens, Ebf, Win, W1, W2, b_in, b1, b2,
                                 cur_in, final_out, Xs, Pv, b, n0, l15, q, c, sub);
    tail_level<1,  false, true >(tokens, Ebf, Win, W1, W2, b_in, b1, b2,
                                 cur_in, final_out, Xs, Pv, b, n0, l15, q, c, sub);
}

extern "C" void kernel_launch(void* const* d_in, const int* in_sizes, int n_in,
                              void* d_out, int out_size, void* d_ws, size_t ws_size,
                              hipStream_t stream) {
    const int*   tokens = (const int*)  d_in[0];
    const float* E      = (const float*)d_in[1];
    const float* W_in   = (const float*)d_in[2];
    const float* b_in   = (const float*)d_in[3];
    const float* W1     = (const float*)d_in[4];
    const float* b1     = (const float*)d_in[5];
    const float* W2     = (const float*)d_in[6];
    const float* b2     = (const float*)d_in[7];
    float* out = (float*)d_out;
    char* ws = (char*)d_ws;

    unsigned short* Ebf   = (unsigned short*)(ws);
    unsigned short* Winbf = (unsigned short*)(ws + 16416768);
    unsigned short* W1bf  = (unsigned short*)(ws + 16809984);
    unsigned short* W2bf  = (unsigned short*)(ws + 16941056);
    unsigned short* curA  = (unsigned short*)(ws + 17072128);
    unsigned short* curB  = (unsigned short*)(ws + 50626560);

    // allow 67.6KB dynamic LDS for the MT=8 instantiation (once per process)
    static bool attr_done = false;
    if (!attr_done) {
        void (*k8)(const int*, const unsigned short*, const unsigned short*,
                   const unsigned short*, const unsigned short*, const float*,
                   const float*, const float*, const unsigned short*,
                   unsigned short*, int, int, int) = tree_level<8>;
        (void)hipFuncSetAttribute(reinterpret_cast<const void*>(k8),
                                  hipFuncAttributeMaxDynamicSharedMemorySize,
                                  128 * XS_STRIDE * 2);
        attr_done = true;
    }

    convert_f32_bf16<<<1024, 256, 0, stream>>>(E, W_in, W1, W2,
                                               Ebf, Winbf, W1bf, W2bf);

    // L=1024 (first level, reads tokens): MT=8, 512 blocks -> curA
    tree_level<8><<<dim3(512), dim3(256), 128 * XS_STRIDE * 2, stream>>>(
        tokens, Ebf, Winbf, W1bf, W2bf, b_in, b1, b2,
        nullptr, curA, 1024, 10, 1);
    // L=512: MT=8, 256 blocks, curA -> curB
    tree_level<8><<<dim3(256), dim3(256), 128 * XS_STRIDE * 2, stream>>>(
        tokens, Ebf, Winbf, W1bf, W2bf, b_in, b1, b2,
        curA, curB, 512, 9, 0);
    // L=256: MT=2, 512 blocks, curB -> curA
    tree_level<2><<<dim3(512), dim3(256), 32 * XS_STRIDE * 2, stream>>>(
        tokens, Ebf, Winbf, W1bf, W2bf, b_in, b1, b2,
        curB, curA, 256, 8, 0);
    // L=128: MT=1, 512 blocks, curA -> curB
    tree_level<1><<<dim3(512), dim3(256), 16 * XS_STRIDE * 2, stream>>>(
        tokens, Ebf, Winbf, W1bf, W2bf, b_in, b1, b2,
        curA, curB, 128, 7, 0);
    // L=64: MT=1, 256 blocks, curB -> curA
    tree_level<1><<<dim3(256), dim3(256), 16 * XS_STRIDE * 2, stream>>>(
        tokens, Ebf, Winbf, W1bf, W2bf, b_in, b1, b2,
        curB, curA, 64, 6, 0);
    // fused tail L=32..1: 64 blocks (one per batch), curA -> out
    tree_tail32<<<dim3(64), dim3(256), 0, stream>>>(
        tokens, Ebf, Winbf, W1bf, W2bf, b_in, b1, b2, curA, out);
}

// Round 11
// 482.159 us; speedup vs baseline: 1.6522x; 1.0118x over previous
//
#include <hip/hip_runtime.h>
#include <stdint.h>

// ---------------------------------------------------------------------------
// aggregated_embedding: heap binary-tree aggregation, 11 levels.
// Per level: out = root + (elu(elu(x@WinT+b_in)@W1T+b1)@W2T+b2), x=[root,left,right]
// bf16 MFMA 16x16x32, fp32 accumulate. Round 13:
//  R10 post-mortem: depth-4 == depth-8 EXACTLY (144us) -> B-load latency is
//  NOT the tail bottleneck. Data-side chain accounts for <=10k cy/level vs
//  58k measured. NEW THEORY: instruction-fetch streaming -- six fully
//  inlined levels = 70-90KB straight-line code >> 32KB I$; every inst is an
//  L2 fetch. Fits: time is data-depth-independent and run-constant.
//  TEST (single variable = code size): ONE __noinline__ runtime-L
//  tail_level_rt called from a '#pragma unroll 1' loop (~10KB, I$-resident
//  after level 1). Xs/Pv are static __shared__ INSIDE the function so LDS
//  address space survives the call boundary (avoids R6's flat-load trap).
//  Data-side logic byte-identical to R10.
// schedule: convert | 1024 MT8 | 512 MT8 | 256 MT2 | 128 MT1 | 64 MT1 | tail32
// ws layout:
//   [0)            Ebf   32064*256 bf16
//   [16,416,768)   Winbf 256*768  bf16   (row-major [n][k] = MFMA B-frag order)
//   [16,809,984)   W1bf  256*256  bf16
//   [16,941,056)   W2bf  256*256  bf16
//   [17,072,128)   curA  64*1024*256 bf16
//   [50,626,560)   curB  64*512*256 bf16
// ---------------------------------------------------------------------------

typedef __attribute__((ext_vector_type(8))) short short8;   // 8 x bf16 frag
typedef __attribute__((ext_vector_type(4))) float f32x4;    // MFMA C/D

#define XS_STRIDE 264   // 256+8 pad: row stride 528B, b128-aligned, 2-way bank alias (free)
#define TOK_N 4095

__device__ __forceinline__ unsigned short f32_to_bf16(float f) {
    union { float f; unsigned u; } v; v.f = f;
    return (unsigned short)((v.u + 0x7fffu + ((v.u >> 16) & 1u)) >> 16);  // RNE
}
__device__ __forceinline__ float bf16_to_f32(unsigned short u) {
    union { unsigned u; float f; } v; v.u = ((unsigned)u) << 16; return v.f;
}

__global__ void convert_f32_bf16(const float* __restrict__ E,
                                 const float* __restrict__ Win,
                                 const float* __restrict__ W1,
                                 const float* __restrict__ W2,
                                 unsigned short* __restrict__ Ebf,
                                 unsigned short* __restrict__ Winbf,
                                 unsigned short* __restrict__ W1bf,
                                 unsigned short* __restrict__ W2bf) {
    const int nE = 32064 * 256, nWin = 256 * 768, nW = 256 * 256;
    const int total4 = (nE + nWin + 2 * nW) >> 2;
    for (int i = blockIdx.x * blockDim.x + threadIdx.x; i < total4;
         i += gridDim.x * blockDim.x) {
        int idx = i << 2;
        const float* src; unsigned short* dst; int off;
        if (idx < nE)                  { src = E;   dst = Ebf;   off = idx; }
        else if (idx < nE + nWin)      { src = Win; dst = Winbf; off = idx - nE; }
        else if (idx < nE + nWin + nW) { src = W1;  dst = W1bf;  off = idx - nE - nWin; }
        else                           { src = W2;  dst = W2bf;  off = idx - nE - nWin - nW; }
        float4 f = *(const float4*)(src + off);
        ushort4 o;
        o.x = f32_to_bf16(f.x); o.y = f32_to_bf16(f.y);
        o.z = f32_to_bf16(f.z); o.w = f32_to_bf16(f.w);
        *(ushort4*)(dst + off) = o;
    }
}

// ---- shared GEMM machinery ------------------------------------------------
template<int MT>
__device__ __forceinline__ void acc_bias_init(f32x4 (&acc)[MT][4],
                                              const float* __restrict__ b,
                                              int n0, int l15) {
    float bv[4];
#pragma unroll
    for (int nt = 0; nt < 4; ++nt) bv[nt] = b[n0 + nt * 16 + l15];
#pragma unroll
    for (int mt = 0; mt < MT; ++mt)
#pragma unroll
        for (int nt = 0; nt < 4; ++nt)
            acc[mt][nt] = (f32x4){bv[nt], bv[nt], bv[nt], bv[nt]};
}

// 8 ksteps of K=256 against a [n][k] weight panel; rolling 2-kstep preload
// (good when TLP hides L2 latency -- the big-level kernels)
template<int MT>
__device__ __forceinline__ void mfma_gemm(const unsigned short* Xs,
                                          f32x4 (&acc)[MT][4],
                                          const unsigned short* __restrict__ base,
                                          int nstride, int kbase,
                                          int l15, int q) {
    short8 bb[2][4];
#pragma unroll
    for (int k = 0; k < 2; ++k)
#pragma unroll
        for (int nt = 0; nt < 4; ++nt)
            bb[k][nt] = *(const short8*)(base + (size_t)(nt * 16) * nstride + kbase + k * 32);
#pragma unroll
    for (int k = 0; k < 8; ++k) {
        short8 a[MT];
#pragma unroll
        for (int mt = 0; mt < MT; ++mt)
            a[mt] = *(const short8*)(&Xs[(mt * 16 + l15) * XS_STRIDE + k * 32 + q * 8]);
#pragma unroll
        for (int mt = 0; mt < MT; ++mt)
#pragma unroll
            for (int nt = 0; nt < 4; ++nt)
                acc[mt][nt] = __builtin_amdgcn_mfma_f32_16x16x32_bf16(
                    a[mt], bb[k & 1][nt], acc[mt][nt], 0, 0, 0);
        if (k + 2 < 8) {
#pragma unroll
            for (int nt = 0; nt < 4; ++nt)
                bb[k & 1][nt] = *(const short8*)(base + (size_t)(nt * 16) * nstride + kbase + (k + 2) * 32);
        }
    }
}

// depth-4 B preload: 2 rounds of 4 ksteps (bb[4][4] = 64 VGPR, 16 loads
// in flight per round). Latency-optimized for the 1-block/CU fused tail.
template<int MT>
__device__ __forceinline__ void mfma_gemm_deep(const unsigned short* Xs,
                                               f32x4 (&acc)[MT][4],
                                               const unsigned short* __restrict__ base,
                                               int nstride, int kbase,
                                               int l15, int q) {
#pragma unroll
    for (int h = 0; h < 2; ++h) {
        short8 bb[4][4];
#pragma unroll
        for (int k = 0; k < 4; ++k)
#pragma unroll
            for (int nt = 0; nt < 4; ++nt)
                bb[k][nt] = *(const short8*)(base + (size_t)(nt * 16) * nstride
                                             + kbase + (h * 4 + k) * 32);
#pragma unroll
        for (int k = 0; k < 4; ++k) {
            short8 a[MT];
#pragma unroll
            for (int mt = 0; mt < MT; ++mt)
                a[mt] = *(const short8*)(&Xs[(mt * 16 + l15) * XS_STRIDE
                                             + (h * 4 + k) * 32 + q * 8]);
#pragma unroll
            for (int mt = 0; mt < MT; ++mt)
#pragma unroll
                for (int nt = 0; nt < 4; ++nt)
                    acc[mt][nt] = __builtin_amdgcn_mfma_f32_16x16x32_bf16(
                        a[mt], bb[k][nt], acc[mt][nt], 0, 0, 0);
        }
    }
}

template<int MT>
__device__ __forceinline__ void elu_store_Xs(unsigned short* Xs,
                                             f32x4 (&acc)[MT][4],
                                             int n0, int l15, int q) {
#pragma unroll
    for (int mt = 0; mt < MT; ++mt)
#pragma unroll
        for (int nt = 0; nt < 4; ++nt)
#pragma unroll
            for (int r = 0; r < 4; ++r) {
                float h = acc[mt][nt][r];
                h = h > 0.f ? h : (__expf(h) - 1.f);
                Xs[(mt * 16 + q * 4 + r) * XS_STRIDE + n0 + nt * 16 + l15] = f32_to_bf16(h);
            }
}

// ---------------------------------------------------------------------------
// tree_level<MT>: R4-exact. block = 256 thr (4 waves), R = MT*16 rows x 256.
// MT=8: 2 waves/EU, dynamic LDS 67.6KB, unchunked 16-deep serial gathers.
// MT<8: 4 waves/EU, register gather prefetch overlapped with GEMM.
// ---------------------------------------------------------------------------
template<int MT>
__global__ __launch_bounds__(256, (MT == 8) ? 2 : 4)
void tree_level(const int* __restrict__ tokens,
                const unsigned short* __restrict__ Ebf,
                const unsigned short* __restrict__ Win,
                const unsigned short* __restrict__ W1,
                const unsigned short* __restrict__ W2,
                const float* __restrict__ b_in,
                const float* __restrict__ b1,
                const float* __restrict__ b2,
                const unsigned short* __restrict__ cur_in,
                unsigned short* __restrict__ cur_out,
                int L, int logL, int first)
{
    constexpr int R = MT * 16;
    constexpr int GITER = R / 8;
    constexpr bool PF = (MT < 8);
    extern __shared__ unsigned short Xs[];

    const int tid  = threadIdx.x;
    const int lane = tid & 63;
    const int wid  = tid >> 6;
    const int l15  = lane & 15;
    const int q    = lane >> 4;
    const int n0   = wid * 64;
    const int blk  = blockIdx.x;
    const int c    = tid & 31;
    const int sub  = tid >> 5;

    auto gsrc = [&](int p, int r) -> const unsigned short* {
        int g = blk * R + r;
        int b = g >> logL;
        int i = g - (b << logL);
        if (p == 0) {
            int tok = tokens[b * TOK_N + (L - 1) + i];
            return Ebf + (size_t)tok * 256;
        } else if (first) {
            int tok = tokens[b * TOK_N + 2047 + 2 * i + (p - 1)];
            return Ebf + (size_t)tok * 256;
        } else {
            return cur_in + ((size_t)b * (2 * L) + 2 * i + (p - 1)) * 256;
        }
    };

    // unchunked serial stage (MT==8): 16 loads in flight (R4-proven)
    auto stage = [&](int p) {
        short8 t[GITER];
#pragma unroll
        for (int it = 0; it < GITER; ++it)
            t[it] = *(const short8*)(gsrc(p, it * 8 + sub) + c * 8);
#pragma unroll
        for (int it = 0; it < GITER; ++it)
            *(short8*)(&Xs[(it * 8 + sub) * XS_STRIDE + c * 8]) = t[it];
    };

    f32x4 acc[MT][4];
    short8 g[PF ? GITER : 1];

    // ---- phase-0 gather (root) ------------------------------------------
    if constexpr (PF) {
#pragma unroll
        for (int it = 0; it < GITER; ++it)
            g[it] = *(const short8*)(gsrc(0, it * 8 + sub) + c * 8);
#pragma unroll
        for (int it = 0; it < GITER; ++it)
            *(short8*)(&Xs[(it * 8 + sub) * XS_STRIDE + c * 8]) = g[it];
    } else {
        stage(0);
    }
    __syncthreads();

    // ---- GEMM1: 3 phases of K=256 against Win (row stride 768) ----------
    acc_bias_init<MT>(acc, b_in, n0, l15);
    const unsigned short* wbase = Win + q * 8 + (size_t)(n0 + l15) * 768;
    for (int p = 0; p < 3; ++p) {
        if constexpr (PF) {
            if (p < 2) {
#pragma unroll
                for (int it = 0; it < GITER; ++it)
                    g[it] = *(const short8*)(gsrc(p + 1, it * 8 + sub) + c * 8);
            }
        }
        mfma_gemm<MT>(Xs, acc, wbase, 768, p * 256, l15, q);
        __syncthreads();
        if (p < 2) {
            if constexpr (PF) {
#pragma unroll
                for (int it = 0; it < GITER; ++it)
                    *(short8*)(&Xs[(it * 8 + sub) * XS_STRIDE + c * 8]) = g[it];
            } else {
                stage(p + 1);
            }
            __syncthreads();
        }
    }

    elu_store_Xs<MT>(Xs, acc, n0, l15, q);
    __syncthreads();

    // ---- GEMM2 (+ root re-gather prefetch if PF) ------------------------
    acc_bias_init<MT>(acc, b1, n0, l15);
    if constexpr (PF) {
#pragma unroll
        for (int it = 0; it < GITER; ++it)
            g[it] = *(const short8*)(gsrc(0, it * 8 + sub) + c * 8);
    }
    mfma_gemm<MT>(Xs, acc, W1 + q * 8 + (size_t)(n0 + l15) * 256, 256, 0, l15, q);
    __syncthreads();

    elu_store_Xs<MT>(Xs, acc, n0, l15, q);
    __syncthreads();

    // ---- GEMM3 ----------------------------------------------------------
    acc_bias_init<MT>(acc, b2, n0, l15);
    mfma_gemm<MT>(Xs, acc, W2 + q * 8 + (size_t)(n0 + l15) * 256, 256, 0, l15, q);
    __syncthreads();
    // park root rows (bf16) in Xs for transposed access by the epilogue
    if constexpr (PF) {
#pragma unroll
        for (int it = 0; it < GITER; ++it)
            *(short8*)(&Xs[(it * 8 + sub) * XS_STRIDE + c * 8]) = g[it];
    } else {
        stage(0);
    }
    __syncthreads();

    // ---- epilogue 3: out = root + H3, coalesced via LDS -----------------
#pragma unroll
    for (int mt = 0; mt < MT; ++mt)
#pragma unroll
        for (int r = 0; r < 4; ++r) {
            int row = mt * 16 + q * 4 + r;
#pragma unroll
            for (int nt = 0; nt < 4; ++nt) {
                int col = n0 + nt * 16 + l15;
                float o = acc[mt][nt][r] + bf16_to_f32(Xs[row * XS_STRIDE + col]);
                Xs[row * XS_STRIDE + col] = f32_to_bf16(o);
            }
        }
    __syncthreads();
#pragma unroll
    for (int it = 0; it < GITER; ++it) {
        int row = it * 8 + sub;
        *(short8*)(cur_out + ((size_t)(blk * R + row)) * 256 + c * 8) =
            *(const short8*)(&Xs[row * XS_STRIDE + c * 8]);
    }
}

// ---------------------------------------------------------------------------
// tail_level_rt: ONE runtime-L copy of the fused-tail level body (I$-resident
// after the first call). 32-row tile, MT=2, 256 thr / 4 waves. Xs/Pv are
// static __shared__ INSIDE the function: LDS address space is preserved
// across the noinline call boundary (Pv traffic stays ds_read/ds_write).
// Data-side logic identical to R10's template version.
// ---------------------------------------------------------------------------
__device__ __attribute__((noinline)) void tail_level_rt(
    const int* __restrict__ tokens,
    const unsigned short* __restrict__ Ebf,
    const unsigned short* __restrict__ Win,
    const unsigned short* __restrict__ W1,
    const unsigned short* __restrict__ W2,
    const float* __restrict__ b_in,
    const float* __restrict__ b1,
    const float* __restrict__ b2,
    const unsigned short* __restrict__ cur_in,
    float* __restrict__ final_out,
    int b, int n0, int l15, int q, int c, int sub,
    int L, int first_lvl, int last_lvl)
{
    constexpr int MT = 2;
    __shared__ unsigned short Xs[32 * XS_STRIDE];   // 16.9 KB
    __shared__ unsigned short Pv[32 * 256];         // 16.0 KB (persists calls)

    const int Lm = L - 1;

    short8 gr[4];                                    // root rows, level-persistent
    auto ld_root = [&]() {
#pragma unroll
        for (int it = 0; it < 4; ++it) {
            int row = it * 8 + sub;
            int il  = row & Lm;
            int tok = tokens[b * TOK_N + Lm + il];
            gr[it] = *(const short8*)(Ebf + (size_t)tok * 256 + c * 8);
        }
    };
    auto park_root = [&]() {
#pragma unroll
        for (int it = 0; it < 4; ++it)
            *(short8*)(&Xs[(it * 8 + sub) * XS_STRIDE + c * 8]) = gr[it];
    };
    auto stg_lr = [&](int p) {
        if (first_lvl) {                             // uniform branch
            short8 t[4];
#pragma unroll
            for (int it = 0; it < 4; ++it) {
                int row = it * 8 + sub;
                int il  = row & Lm;
                t[it] = *(const short8*)(cur_in + ((size_t)b * (2 * L) + 2 * il + (p - 1)) * 256 + c * 8);
            }
#pragma unroll
            for (int it = 0; it < 4; ++it)
                *(short8*)(&Xs[(it * 8 + sub) * XS_STRIDE + c * 8]) = t[it];
        } else {
#pragma unroll
            for (int it = 0; it < 4; ++it) {
                int row = it * 8 + sub;
                int il  = row & Lm;
                short8 t = *(const short8*)(&Pv[(2 * il + (p - 1)) * 256 + c * 8]);
                *(short8*)(&Xs[row * XS_STRIDE + c * 8]) = t;
            }
        }
    };

    f32x4 acc[MT][4];

    ld_root();
    park_root();
    __syncthreads();

    acc_bias_init<MT>(acc, b_in, n0, l15);
    const unsigned short* wbase = Win + q * 8 + (size_t)(n0 + l15) * 768;
#pragma unroll 1
    for (int p = 0; p < 3; ++p) {                    // ONE code copy of GEMM1
        mfma_gemm_deep<MT>(Xs, acc, wbase, 768, p * 256, l15, q);
        __syncthreads();
        if (p < 2) { stg_lr(p + 1); __syncthreads(); }
    }

    elu_store_Xs<MT>(Xs, acc, n0, l15, q);
    __syncthreads();

    acc_bias_init<MT>(acc, b1, n0, l15);
    mfma_gemm_deep<MT>(Xs, acc, W1 + q * 8 + (size_t)(n0 + l15) * 256, 256, 0, l15, q);
    __syncthreads();

    elu_store_Xs<MT>(Xs, acc, n0, l15, q);
    __syncthreads();

    acc_bias_init<MT>(acc, b2, n0, l15);
    mfma_gemm_deep<MT>(Xs, acc, W2 + q * 8 + (size_t)(n0 + l15) * 256, 256, 0, l15, q);
    __syncthreads();
    park_root();                                     // from regs, no re-gather
    __syncthreads();

    if (last_lvl) {
#pragma unroll
        for (int mt = 0; mt < MT; ++mt)
#pragma unroll
            for (int r = 0; r < 4; ++r) {
                int row = mt * 16 + q * 4 + r;
                if (row == 0) {
#pragma unroll
                    for (int nt = 0; nt < 4; ++nt) {
                        int col = n0 + nt * 16 + l15;
                        final_out[(size_t)b * 256 + col] =
                            acc[mt][nt][r] + bf16_to_f32(Xs[row * XS_STRIDE + col]);
                    }
                }
            }
    } else {
#pragma unroll
        for (int mt = 0; mt < MT; ++mt)
#pragma unroll
            for (int r = 0; r < 4; ++r) {
                int row = mt * 16 + q * 4 + r;
                if (row < L) {
#pragma unroll
                    for (int nt = 0; nt < 4; ++nt) {
                        int col = n0 + nt * 16 + l15;
                        float o = acc[mt][nt][r] + bf16_to_f32(Xs[row * XS_STRIDE + col]);
                        Pv[row * 256 + col] = f32_to_bf16(o);
                    }
                }
            }
    }
    __syncthreads();   // Pv complete before next level stages from it
}

// fused tail L=32..1: 64 blocks (one per batch), 256 thr.
__global__ __launch_bounds__(256, 2)
void tree_tail32(const int* __restrict__ tokens,
                 const unsigned short* __restrict__ Ebf,
                 const unsigned short* __restrict__ Win,
                 const unsigned short* __restrict__ W1,
                 const unsigned short* __restrict__ W2,
                 const float* __restrict__ b_in,
                 const float* __restrict__ b1,
                 const float* __restrict__ b2,
                 const unsigned short* __restrict__ cur_in,  // L=64 output
                 float* __restrict__ final_out)
{
    const int tid  = threadIdx.x;
    const int lane = tid & 63;
    const int wid  = tid >> 6;
    const int l15  = lane & 15;
    const int q    = lane >> 4;
    const int n0   = wid * 64;
    const int b    = blockIdx.x;
    const int c    = tid & 31;
    const int sub  = tid >> 5;

#pragma unroll 1
    for (int L = 32; L >= 1; L >>= 1) {
        tail_level_rt(tokens, Ebf, Win, W1, W2, b_in, b1, b2,
                      cur_in, final_out, b, n0, l15, q, c, sub,
                      L, L == 32, L == 1);
    }
}

extern "C" void kernel_launch(void* const* d_in, const int* in_sizes, int n_in,
                              void* d_out, int out_size, void* d_ws, size_t ws_size,
                              hipStream_t stream) {
    const int*   tokens = (const int*)  d_in[0];
    const float* E      = (const float*)d_in[1];
    const float* W_in   = (const float*)d_in[2];
    const float* b_in   = (const float*)d_in[3];
    const float* W1     = (const float*)d_in[4];
    const float* b1     = (const float*)d_in[5];
    const float* W2     = (const float*)d_in[6];
    const float* b2     = (const float*)d_in[7];
    float* out = (float*)d_out;
    char* ws = (char*)d_ws;

    unsigned short* Ebf   = (unsigned short*)(ws);
    unsigned short* Winbf = (unsigned short*)(ws + 16416768);
    unsigned short* W1bf  = (unsigned short*)(ws + 16809984);
    unsigned short* W2bf  = (unsigned short*)(ws + 16941056);
    unsigned short* curA  = (unsigned short*)(ws + 17072128);
    unsigned short* curB  = (unsigned short*)(ws + 50626560);

    // allow 67.6KB dynamic LDS for the MT=8 instantiation (once per process)
    static bool attr_done = false;
    if (!attr_done) {
        void (*k8)(const int*, const unsigned short*, const unsigned short*,
                   const unsigned short*, const unsigned short*, const float*,
                   const float*, const float*, const unsigned short*,
                   unsigned short*, int, int, int) = tree_level<8>;
        (void)hipFuncSetAttribute(reinterpret_cast<const void*>(k8),
                                  hipFuncAttributeMaxDynamicSharedMemorySize,
                                  128 * XS_STRIDE * 2);
        attr_done = true;
    }

    convert_f32_bf16<<<1024, 256, 0, stream>>>(E, W_in, W1, W2,
                                               Ebf, Winbf, W1bf, W2bf);

    // L=1024 (first level, reads tokens): MT=8, 512 blocks -> curA
    tree_level<8><<<dim3(512), dim3(256), 128 * XS_STRIDE * 2, stream>>>(
        tokens, Ebf, Winbf, W1bf, W2bf, b_in, b1, b2,
        nullptr, curA, 1024, 10, 1);
    // L=512: MT=8, 256 blocks, curA -> curB
    tree_level<8><<<dim3(256), dim3(256), 128 * XS_STRIDE * 2, stream>>>(
        tokens, Ebf, Winbf, W1bf, W2bf, b_in, b1, b2,
        curA, curB, 512, 9, 0);
    // L=256: MT=2, 512 blocks, curB -> curA
    tree_level<2><<<dim3(512), dim3(256), 32 * XS_STRIDE * 2, stream>>>(
        tokens, Ebf, Winbf, W1bf, W2bf, b_in, b1, b2,
        curB, curA, 256, 8, 0);
    // L=128: MT=1, 512 blocks, curA -> curB
    tree_level<1><<<dim3(512), dim3(256), 16 * XS_STRIDE * 2, stream>>>(
        tokens, Ebf, Winbf, W1bf, W2bf, b_in, b1, b2,
        curA, curB, 128, 7, 0);
    // L=64: MT=1, 256 blocks, curB -> curA
    tree_level<1><<<dim3(256), dim3(256), 16 * XS_STRIDE * 2, stream>>>(
        tokens, Ebf, Winbf, W1bf, W2bf, b_in, b1, b2,
        curB, curA, 64, 6, 0);
    // fused tail L=32..1: 64 blocks (one per batch), curA -> out
    tree_tail32<<<dim3(64), dim3(256), 0, stream>>>(
        tokens, Ebf, Winbf, W1bf, W2bf, b_in, b1, b2, curA, out);
}

// Round 12
// 479.700 us; speedup vs baseline: 1.6606x; 1.0051x over previous
//
#include <hip/hip_runtime.h>
#include <stdint.h>

// ---------------------------------------------------------------------------
// aggregated_embedding: heap binary-tree aggregation, 11 levels.
// Per level: out = root + (elu(elu(x@WinT+b_in)@W1T+b1)@W2T+b2), x=[root,left,right]
// bf16 MFMA 16x16x32, fp32 accumulate. Round 14:
//  R10/R11 refuted B-depth, I$-size and spill theories for the tail
//  (depth4==depth8; code 6x smaller + WRITE 64B => only -4us). Surviving
//  model: tail time ~ #serialized wait-points x exposed round-trip
//  (~12/level x ~2us at 1 block/CU, no TLP).
//  FIX: wait-point-minimized tail. GEMM1 A-fragments read DIRECTLY from
//  LDS (Rt root table + parity-split Pv prev-output) -- no staging copies,
//  no per-level gathers. Up-front: one stage of cur_in->Pv + all 63 root
//  rows->Rt. Per level: 4 barriers (was 12), zero stagings (was 3+repark).
//  Pv parity-split (even rows->slot 0..31, odd->32..63) keeps A-reads at
//  stride 264 = 2-way bank alias (free). Rows>=L read finite garbage,
//  masked at store. Big levels: R4-proven dispatches, untouched.
// schedule: convert | 1024 MT8 | 512 MT8 | 256 MT2 | 128 MT1 | 64 MT1 | tail32
// ws layout:
//   [0)            Ebf   32064*256 bf16
//   [16,416,768)   Winbf 256*768  bf16   (row-major [n][k] = MFMA B-frag order)
//   [16,809,984)   W1bf  256*256  bf16
//   [16,941,056)   W2bf  256*256  bf16
//   [17,072,128)   curA  64*1024*256 bf16
//   [50,626,560)   curB  64*512*256 bf16
// ---------------------------------------------------------------------------

typedef __attribute__((ext_vector_type(8))) short short8;   // 8 x bf16 frag
typedef __attribute__((ext_vector_type(4))) float f32x4;    // MFMA C/D

#define XS_STRIDE 264   // 256+8 pad: row stride 528B, b128-aligned, 2-way bank alias (free)
#define TOK_N 4095

__device__ __forceinline__ unsigned short f32_to_bf16(float f) {
    union { float f; unsigned u; } v; v.f = f;
    return (unsigned short)((v.u + 0x7fffu + ((v.u >> 16) & 1u)) >> 16);  // RNE
}
__device__ __forceinline__ float bf16_to_f32(unsigned short u) {
    union { unsigned u; float f; } v; v.u = ((unsigned)u) << 16; return v.f;
}

__global__ void convert_f32_bf16(const float* __restrict__ E,
                                 const float* __restrict__ Win,
                                 const float* __restrict__ W1,
                                 const float* __restrict__ W2,
                                 unsigned short* __restrict__ Ebf,
                                 unsigned short* __restrict__ Winbf,
                                 unsigned short* __restrict__ W1bf,
                                 unsigned short* __restrict__ W2bf) {
    const int nE = 32064 * 256, nWin = 256 * 768, nW = 256 * 256;
    const int total4 = (nE + nWin + 2 * nW) >> 2;
    for (int i = blockIdx.x * blockDim.x + threadIdx.x; i < total4;
         i += gridDim.x * blockDim.x) {
        int idx = i << 2;
        const float* src; unsigned short* dst; int off;
        if (idx < nE)                  { src = E;   dst = Ebf;   off = idx; }
        else if (idx < nE + nWin)      { src = Win; dst = Winbf; off = idx - nE; }
        else if (idx < nE + nWin + nW) { src = W1;  dst = W1bf;  off = idx - nE - nWin; }
        else                           { src = W2;  dst = W2bf;  off = idx - nE - nWin - nW; }
        float4 f = *(const float4*)(src + off);
        ushort4 o;
        o.x = f32_to_bf16(f.x); o.y = f32_to_bf16(f.y);
        o.z = f32_to_bf16(f.z); o.w = f32_to_bf16(f.w);
        *(ushort4*)(dst + off) = o;
    }
}

// ---- shared GEMM machinery ------------------------------------------------
template<int MT>
__device__ __forceinline__ void acc_bias_init(f32x4 (&acc)[MT][4],
                                              const float* __restrict__ b,
                                              int n0, int l15) {
    float bv[4];
#pragma unroll
    for (int nt = 0; nt < 4; ++nt) bv[nt] = b[n0 + nt * 16 + l15];
#pragma unroll
    for (int mt = 0; mt < MT; ++mt)
#pragma unroll
        for (int nt = 0; nt < 4; ++nt)
            acc[mt][nt] = (f32x4){bv[nt], bv[nt], bv[nt], bv[nt]};
}

// 8 ksteps of K=256 against a [n][k] weight panel; rolling 2-kstep preload
// (good when TLP hides L2 latency -- the big-level kernels)
template<int MT>
__device__ __forceinline__ void mfma_gemm(const unsigned short* Xs,
                                          f32x4 (&acc)[MT][4],
                                          const unsigned short* __restrict__ base,
                                          int nstride, int kbase,
                                          int l15, int q) {
    short8 bb[2][4];
#pragma unroll
    for (int k = 0; k < 2; ++k)
#pragma unroll
        for (int nt = 0; nt < 4; ++nt)
            bb[k][nt] = *(const short8*)(base + (size_t)(nt * 16) * nstride + kbase + k * 32);
#pragma unroll
    for (int k = 0; k < 8; ++k) {
        short8 a[MT];
#pragma unroll
        for (int mt = 0; mt < MT; ++mt)
            a[mt] = *(const short8*)(&Xs[(mt * 16 + l15) * XS_STRIDE + k * 32 + q * 8]);
#pragma unroll
        for (int mt = 0; mt < MT; ++mt)
#pragma unroll
            for (int nt = 0; nt < 4; ++nt)
                acc[mt][nt] = __builtin_amdgcn_mfma_f32_16x16x32_bf16(
                    a[mt], bb[k & 1][nt], acc[mt][nt], 0, 0, 0);
        if (k + 2 < 8) {
#pragma unroll
            for (int nt = 0; nt < 4; ++nt)
                bb[k & 1][nt] = *(const short8*)(base + (size_t)(nt * 16) * nstride + kbase + (k + 2) * 32);
        }
    }
}

// tail GEMM: K=256 sub-GEMM, A read directly from an LDS region at row
// stride 264 (base pre-offset). Depth-4 B preload (2 rounds x 16 loads).
template<int MT>
__device__ __forceinline__ void gemm_lds(const unsigned short* A,   // LDS
                                         f32x4 (&acc)[MT][4],
                                         const unsigned short* __restrict__ wb,
                                         int nstride, int kbase,
                                         int l15, int q) {
#pragma unroll
    for (int h = 0; h < 2; ++h) {
        short8 bb[4][4];
#pragma unroll
        for (int k = 0; k < 4; ++k)
#pragma unroll
            for (int nt = 0; nt < 4; ++nt)
                bb[k][nt] = *(const short8*)(wb + (size_t)(nt * 16) * nstride
                                             + kbase + (h * 4 + k) * 32);
#pragma unroll
        for (int k = 0; k < 4; ++k) {
            short8 a[MT];
#pragma unroll
            for (int mt = 0; mt < MT; ++mt)
                a[mt] = *(const short8*)(&A[(mt * 16 + l15) * XS_STRIDE
                                            + (h * 4 + k) * 32 + q * 8]);
#pragma unroll
            for (int mt = 0; mt < MT; ++mt)
#pragma unroll
                for (int nt = 0; nt < 4; ++nt)
                    acc[mt][nt] = __builtin_amdgcn_mfma_f32_16x16x32_bf16(
                        a[mt], bb[k][nt], acc[mt][nt], 0, 0, 0);
        }
    }
}

template<int MT>
__device__ __forceinline__ void elu_store_Xs(unsigned short* Xs,
                                             f32x4 (&acc)[MT][4],
                                             int n0, int l15, int q) {
#pragma unroll
    for (int mt = 0; mt < MT; ++mt)
#pragma unroll
        for (int nt = 0; nt < 4; ++nt)
#pragma unroll
            for (int r = 0; r < 4; ++r) {
                float h = acc[mt][nt][r];
                h = h > 0.f ? h : (__expf(h) - 1.f);
                Xs[(mt * 16 + q * 4 + r) * XS_STRIDE + n0 + nt * 16 + l15] = f32_to_bf16(h);
            }
}

// ---------------------------------------------------------------------------
// tree_level<MT>: R4-exact. block = 256 thr (4 waves), R = MT*16 rows x 256.
// MT=8: 2 waves/EU, dynamic LDS 67.6KB, unchunked 16-deep serial gathers.
// MT<8: 4 waves/EU, register gather prefetch overlapped with GEMM.
// ---------------------------------------------------------------------------
template<int MT>
__global__ __launch_bounds__(256, (MT == 8) ? 2 : 4)
void tree_level(const int* __restrict__ tokens,
                const unsigned short* __restrict__ Ebf,
                const unsigned short* __restrict__ Win,
                const unsigned short* __restrict__ W1,
                const unsigned short* __restrict__ W2,
                const float* __restrict__ b_in,
                const float* __restrict__ b1,
                const float* __restrict__ b2,
                const unsigned short* __restrict__ cur_in,
                unsigned short* __restrict__ cur_out,
                int L, int logL, int first)
{
    constexpr int R = MT * 16;
    constexpr int GITER = R / 8;
    constexpr bool PF = (MT < 8);
    extern __shared__ unsigned short Xs[];

    const int tid  = threadIdx.x;
    const int lane = tid & 63;
    const int wid  = tid >> 6;
    const int l15  = lane & 15;
    const int q    = lane >> 4;
    const int n0   = wid * 64;
    const int blk  = blockIdx.x;
    const int c    = tid & 31;
    const int sub  = tid >> 5;

    auto gsrc = [&](int p, int r) -> const unsigned short* {
        int g = blk * R + r;
        int b = g >> logL;
        int i = g - (b << logL);
        if (p == 0) {
            int tok = tokens[b * TOK_N + (L - 1) + i];
            return Ebf + (size_t)tok * 256;
        } else if (first) {
            int tok = tokens[b * TOK_N + 2047 + 2 * i + (p - 1)];
            return Ebf + (size_t)tok * 256;
        } else {
            return cur_in + ((size_t)b * (2 * L) + 2 * i + (p - 1)) * 256;
        }
    };

    // unchunked serial stage (MT==8): 16 loads in flight (R4-proven)
    auto stage = [&](int p) {
        short8 t[GITER];
#pragma unroll
        for (int it = 0; it < GITER; ++it)
            t[it] = *(const short8*)(gsrc(p, it * 8 + sub) + c * 8);
#pragma unroll
        for (int it = 0; it < GITER; ++it)
            *(short8*)(&Xs[(it * 8 + sub) * XS_STRIDE + c * 8]) = t[it];
    };

    f32x4 acc[MT][4];
    short8 g[PF ? GITER : 1];

    // ---- phase-0 gather (root) ------------------------------------------
    if constexpr (PF) {
#pragma unroll
        for (int it = 0; it < GITER; ++it)
            g[it] = *(const short8*)(gsrc(0, it * 8 + sub) + c * 8);
#pragma unroll
        for (int it = 0; it < GITER; ++it)
            *(short8*)(&Xs[(it * 8 + sub) * XS_STRIDE + c * 8]) = g[it];
    } else {
        stage(0);
    }
    __syncthreads();

    // ---- GEMM1: 3 phases of K=256 against Win (row stride 768) ----------
    acc_bias_init<MT>(acc, b_in, n0, l15);
    const unsigned short* wbase = Win + q * 8 + (size_t)(n0 + l15) * 768;
    for (int p = 0; p < 3; ++p) {
        if constexpr (PF) {
            if (p < 2) {
#pragma unroll
                for (int it = 0; it < GITER; ++it)
                    g[it] = *(const short8*)(gsrc(p + 1, it * 8 + sub) + c * 8);
            }
        }
        mfma_gemm<MT>(Xs, acc, wbase, 768, p * 256, l15, q);
        __syncthreads();
        if (p < 2) {
            if constexpr (PF) {
#pragma unroll
                for (int it = 0; it < GITER; ++it)
                    *(short8*)(&Xs[(it * 8 + sub) * XS_STRIDE + c * 8]) = g[it];
            } else {
                stage(p + 1);
            }
            __syncthreads();
        }
    }

    elu_store_Xs<MT>(Xs, acc, n0, l15, q);
    __syncthreads();

    // ---- GEMM2 (+ root re-gather prefetch if PF) ------------------------
    acc_bias_init<MT>(acc, b1, n0, l15);
    if constexpr (PF) {
#pragma unroll
        for (int it = 0; it < GITER; ++it)
            g[it] = *(const short8*)(gsrc(0, it * 8 + sub) + c * 8);
    }
    mfma_gemm<MT>(Xs, acc, W1 + q * 8 + (size_t)(n0 + l15) * 256, 256, 0, l15, q);
    __syncthreads();

    elu_store_Xs<MT>(Xs, acc, n0, l15, q);
    __syncthreads();

    // ---- GEMM3 ----------------------------------------------------------
    acc_bias_init<MT>(acc, b2, n0, l15);
    mfma_gemm<MT>(Xs, acc, W2 + q * 8 + (size_t)(n0 + l15) * 256, 256, 0, l15, q);
    __syncthreads();
    // park root rows (bf16) in Xs for transposed access by the epilogue
    if constexpr (PF) {
#pragma unroll
        for (int it = 0; it < GITER; ++it)
            *(short8*)(&Xs[(it * 8 + sub) * XS_STRIDE + c * 8]) = g[it];
    } else {
        stage(0);
    }
    __syncthreads();

    // ---- epilogue 3: out = root + H3, coalesced via LDS -----------------
#pragma unroll
    for (int mt = 0; mt < MT; ++mt)
#pragma unroll
        for (int r = 0; r < 4; ++r) {
            int row = mt * 16 + q * 4 + r;
#pragma unroll
            for (int nt = 0; nt < 4; ++nt) {
                int col = n0 + nt * 16 + l15;
                float o = acc[mt][nt][r] + bf16_to_f32(Xs[row * XS_STRIDE + col]);
                Xs[row * XS_STRIDE + col] = f32_to_bf16(o);
            }
        }
    __syncthreads();
#pragma unroll
    for (int it = 0; it < GITER; ++it) {
        int row = it * 8 + sub;
        *(short8*)(cur_out + ((size_t)(blk * R + row)) * 256 + c * 8) =
            *(const short8*)(&Xs[row * XS_STRIDE + c * 8]);
    }
}

// ---------------------------------------------------------------------------
// tail_lvl<L,LAST>: one fused-tail level, wait-point-minimized.
// GEMM1 A-operands read directly from Rt (roots, offset L-1) and Pv
// (parity-split prev output: even rows in slots 0..31, odd in 32..63).
// 4 barriers/level, zero staging. Rows>=L read finite garbage, masked.
// ---------------------------------------------------------------------------
template<int L, bool LAST>
__device__ __forceinline__ void tail_lvl(
    const unsigned short* __restrict__ Win,
    const unsigned short* __restrict__ W1,
    const unsigned short* __restrict__ W2,
    const float* __restrict__ b_in,
    const float* __restrict__ b1,
    const float* __restrict__ b2,
    float* __restrict__ final_out,
    unsigned short* Xs, unsigned short* Pv, const unsigned short* Rt,
    int b, int n0, int l15, int q)
{
    constexpr int MT = 2;
    f32x4 acc[MT][4];

    // ---- GEMM1: K=768 as 3 sub-GEMMs, A direct from LDS, no barriers ----
    acc_bias_init<MT>(acc, b_in, n0, l15);
    const unsigned short* wbase = Win + q * 8 + (size_t)(n0 + l15) * 768;
    gemm_lds<MT>(Rt + (L - 1) * XS_STRIDE, acc, wbase, 768, 0,   l15, q); // root
    gemm_lds<MT>(Pv,                       acc, wbase, 768, 256, l15, q); // left
    gemm_lds<MT>(Pv + 32 * XS_STRIDE,      acc, wbase, 768, 512, l15, q); // right

    elu_store_Xs<MT>(Xs, acc, n0, l15, q);
    __syncthreads();                       // (1) Xs ready; all GEMM1 Pv reads done

    acc_bias_init<MT>(acc, b1, n0, l15);
    gemm_lds<MT>(Xs, acc, W1 + q * 8 + (size_t)(n0 + l15) * 256, 256, 0, l15, q);
    __syncthreads();                       // (2) all Xs reads done before elu2

    elu_store_Xs<MT>(Xs, acc, n0, l15, q);
    __syncthreads();                       // (3) Xs ready

    acc_bias_init<MT>(acc, b2, n0, l15);
    gemm_lds<MT>(Xs, acc, W2 + q * 8 + (size_t)(n0 + l15) * 256, 256, 0, l15, q);

    // ---- epilogue: out = root(Rt) + H3; parity-split into Pv / final ----
    if constexpr (LAST) {
#pragma unroll
        for (int mt = 0; mt < MT; ++mt)
#pragma unroll
            for (int r = 0; r < 4; ++r) {
                int row = mt * 16 + q * 4 + r;
                if (row == 0) {
#pragma unroll
                    for (int nt = 0; nt < 4; ++nt) {
                        int col = n0 + nt * 16 + l15;
                        final_out[(size_t)b * 256 + col] =
                            acc[mt][nt][r] + bf16_to_f32(Rt[(L - 1) * XS_STRIDE + col]);
                    }
                }
            }
    } else {
#pragma unroll
        for (int mt = 0; mt < MT; ++mt)
#pragma unroll
            for (int r = 0; r < 4; ++r) {
                int row = mt * 16 + q * 4 + r;
                if (row < L) {
                    int slot = (row >> 1) + (row & 1) * 32;
#pragma unroll
                    for (int nt = 0; nt < 4; ++nt) {
                        int col = n0 + nt * 16 + l15;
                        float o = acc[mt][nt][r]
                                + bf16_to_f32(Rt[(L - 1 + row) * XS_STRIDE + col]);
                        Pv[slot * XS_STRIDE + col] = f32_to_bf16(o);
                    }
                }
            }
    }
    __syncthreads();                       // (4) Pv ready for next level
}

// fused tail L=32..1: 64 blocks (one per batch), 256 thr, dyn LDS 84.5KB.
__global__ __launch_bounds__(256, 2)
void tree_tail32(const int* __restrict__ tokens,
                 const unsigned short* __restrict__ Ebf,
                 const unsigned short* __restrict__ Win,
                 const unsigned short* __restrict__ W1,
                 const unsigned short* __restrict__ W2,
                 const float* __restrict__ b_in,
                 const float* __restrict__ b1,
                 const float* __restrict__ b2,
                 const unsigned short* __restrict__ cur_in,  // L=64 output
                 float* __restrict__ final_out)
{
    extern __shared__ unsigned short lds[];
    unsigned short* Xs = lds;                         // [32][264] elu tmp
    unsigned short* Pv = lds + 32 * XS_STRIDE;        // [64][264] parity-split
    unsigned short* Rt = lds + 96 * XS_STRIDE;        // [64][264] roots 0..62

    const int tid  = threadIdx.x;
    const int lane = tid & 63;
    const int wid  = tid >> 6;
    const int l15  = lane & 15;
    const int q    = lane >> 4;
    const int n0   = wid * 64;
    const int b    = blockIdx.x;
    const int c    = tid & 31;
    const int sub  = tid >> 5;

    // ---- up-front stage: cur_in(64 rows)->Pv parity-split; roots 0..62->Rt
    {
        short8 tp[8], tr[8];
#pragma unroll
        for (int it = 0; it < 8; ++it) {
            int r = it * 8 + sub;
            tp[it] = *(const short8*)(cur_in + ((size_t)b * 64 + r) * 256 + c * 8);
        }
#pragma unroll
        for (int it = 0; it < 8; ++it) {
            int r = it * 8 + sub;
            if (r < 63) {
                int tok = tokens[b * TOK_N + r];
                tr[it] = *(const short8*)(Ebf + (size_t)tok * 256 + c * 8);
            }
        }
#pragma unroll
        for (int it = 0; it < 8; ++it) {
            int r = it * 8 + sub;
            int slot = (r >> 1) + (r & 1) * 32;
            *(short8*)(&Pv[slot * XS_STRIDE + c * 8]) = tp[it];
        }
#pragma unroll
        for (int it = 0; it < 8; ++it) {
            int r = it * 8 + sub;
            if (r < 63)
                *(short8*)(&Rt[r * XS_STRIDE + c * 8]) = tr[it];
        }
    }
    __syncthreads();

    tail_lvl<32, false>(Win, W1, W2, b_in, b1, b2, final_out, Xs, Pv, Rt, b, n0, l15, q);
    tail_lvl<16, false>(Win, W1, W2, b_in, b1, b2, final_out, Xs, Pv, Rt, b, n0, l15, q);
    tail_lvl<8,  false>(Win, W1, W2, b_in, b1, b2, final_out, Xs, Pv, Rt, b, n0, l15, q);
    tail_lvl<4,  false>(Win, W1, W2, b_in, b1, b2, final_out, Xs, Pv, Rt, b, n0, l15, q);
    tail_lvl<2,  false>(Win, W1, W2, b_in, b1, b2, final_out, Xs, Pv, Rt, b, n0, l15, q);
    tail_lvl<1,  true >(Win, W1, W2, b_in, b1, b2, final_out, Xs, Pv, Rt, b, n0, l15, q);
}

extern "C" void kernel_launch(void* const* d_in, const int* in_sizes, int n_in,
                              void* d_out, int out_size, void* d_ws, size_t ws_size,
                              hipStream_t stream) {
    const int*   tokens = (const int*)  d_in[0];
    const float* E      = (const float*)d_in[1];
    const float* W_in   = (const float*)d_in[2];
    const float* b_in   = (const float*)d_in[3];
    const float* W1     = (const float*)d_in[4];
    const float* b1     = (const float*)d_in[5];
    const float* W2     = (const float*)d_in[6];
    const float* b2     = (const float*)d_in[7];
    float* out = (float*)d_out;
    char* ws = (char*)d_ws;

    unsigned short* Ebf   = (unsigned short*)(ws);
    unsigned short* Winbf = (unsigned short*)(ws + 16416768);
    unsigned short* W1bf  = (unsigned short*)(ws + 16809984);
    unsigned short* W2bf  = (unsigned short*)(ws + 16941056);
    unsigned short* curA  = (unsigned short*)(ws + 17072128);
    unsigned short* curB  = (unsigned short*)(ws + 50626560);

    const int TAIL_LDS = 160 * XS_STRIDE * 2;   // 84,480 B

    // allow >64KB dynamic LDS (once per process)
    static bool attr_done = false;
    if (!attr_done) {
        void (*k8)(const int*, const unsigned short*, const unsigned short*,
                   const unsigned short*, const unsigned short*, const float*,
                   const float*, const float*, const unsigned short*,
                   unsigned short*, int, int, int) = tree_level<8>;
        (void)hipFuncSetAttribute(reinterpret_cast<const void*>(k8),
                                  hipFuncAttributeMaxDynamicSharedMemorySize,
                                  128 * XS_STRIDE * 2);
        (void)hipFuncSetAttribute(reinterpret_cast<const void*>(&tree_tail32),
                                  hipFuncAttributeMaxDynamicSharedMemorySize,
                                  TAIL_LDS);
        attr_done = true;
    }

    convert_f32_bf16<<<1024, 256, 0, stream>>>(E, W_in, W1, W2,
                                               Ebf, Winbf, W1bf, W2bf);

    // L=1024 (first level, reads tokens): MT=8, 512 blocks -> curA
    tree_level<8><<<dim3(512), dim3(256), 128 * XS_STRIDE * 2, stream>>>(
        tokens, Ebf, Winbf, W1bf, W2bf, b_in, b1, b2,
        nullptr, curA, 1024, 10, 1);
    // L=512: MT=8, 256 blocks, curA -> curB
    tree_level<8><<<dim3(256), dim3(256), 128 * XS_STRIDE * 2, stream>>>(
        tokens, Ebf, Winbf, W1bf, W2bf, b_in, b1, b2,
        curA, curB, 512, 9, 0);
    // L=256: MT=2, 512 blocks, curB -> curA
    tree_level<2><<<dim3(512), dim3(256), 32 * XS_STRIDE * 2, stream>>>(
        tokens, Ebf, Winbf, W1bf, W2bf, b_in, b1, b2,
        curB, curA, 256, 8, 0);
    // L=128: MT=1, 512 blocks, curA -> curB
    tree_level<1><<<dim3(512), dim3(256), 16 * XS_STRIDE * 2, stream>>>(
        tokens, Ebf, Winbf, W1bf, W2bf, b_in, b1, b2,
        curA, curB, 128, 7, 0);
    // L=64: MT=1, 256 blocks, curB -> curA
    tree_level<1><<<dim3(256), dim3(256), 16 * XS_STRIDE * 2, stream>>>(
        tokens, Ebf, Winbf, W1bf, W2bf, b_in, b1, b2,
        curB, curA, 64, 6, 0);
    // fused tail L=32..1: 64 blocks (one per batch), curA -> out
    tree_tail32<<<dim3(64), dim3(256), TAIL_LDS, stream>>>(
        tokens, Ebf, Winbf, W1bf, W2bf, b_in, b1, b2, curA, out);
}